// Round 9
// baseline (309.725 us; speedup 1.0000x reference)
//
#include <hip/hip_runtime.h>

typedef unsigned short u16;
typedef unsigned int   u32;
typedef __attribute__((ext_vector_type(8))) short short8;
typedef __attribute__((ext_vector_type(4))) float f32x4;

// ---------------- ws layout (float element offsets) ----------------
#define OFF_XPS   0            // 10000*128 (gate-permuted xp story)
#define OFF_XPQ   1280000      // 10000*128 (gate-permuted xp question)
#define OFF_QST   2560000      // 512*32
#define OFF_PI    2576384      // 512*20*256
#define OFF_PJ    5197824      // 512*20*256
#define OFF_QA    7819264      // 512*256
#define OFF_TGA   7950336      // 20*256
#define OFF_TGB   7955456      // 20*256
#define OFF_WB    7960576      // u16 x 196608 (g2/g3/g4 bf16)
#define OFF_STB   8058880      // u16 x 327680 (story h bf16)
#define OFF_WAB   8222720      // u16 x 8192
#define OFF_WBB   8226816      // u16 x 8192
#define OFF_WHHS  8230912      // u16 x 4096
#define OFF_WHHQ  8232960      // u16 x 4096
#define OFF_WF1   8235008      // u16 x 65536
#define OFF_WF2   8267776      // u16 x 131072
#define OFF_WF3   8333312      // u16 x 524288 (1024x512, zero-padded)
// aliased into XPS/XPQ region (dead after lstm):
#define OFF_SGP   0            // 5*256*512 fl  [t][b][h]
#define OFF_SGB   655360       // u16 x 131072 (sum_g bf16 [b][256])
#define OFF_ACT1  720896       // u16 x 131072 ([b][256])
#define OFF_ACT2  786432       // u16 x 262144 ([b][512])

__device__ __forceinline__ u16 f2bf(float f){
  union { float f; u32 u; } v; v.f = f;
  u32 u = v.u;
  u32 r = u + 0x7fffu + ((u >> 16) & 1u);
  return (u16)(r >> 16);
}
__device__ __forceinline__ u32 pack2(float a, float b){
  u32 r;
  asm("v_cvt_pk_bf16_f32 %0, %1, %2" : "=v"(r) : "v"(a), "v"(b));
  return r;
}
__device__ __forceinline__ float sigm(float x){
  return __builtin_amdgcn_rcpf(1.f + __expf(-x));
}

// ---------------- prep_xp: xp[v][g] tables, W staged in LDS ----------------
__global__ __launch_bounds__(256) void prep_xp_kernel(
    const float* __restrict__ emb,
    const float* __restrict__ swih, const float* __restrict__ sbih, const float* __restrict__ sbhh,
    const float* __restrict__ qwih, const float* __restrict__ qbih, const float* __restrict__ qbhh,
    float* __restrict__ xps, float* __restrict__ xpq)
{
  __shared__ float wl[4096];
  __shared__ float bl[128];
  const int tid = threadIdx.x;
  const bool isq = blockIdx.y;
  const float* wih = isq ? qwih : swih;
  const float* bih = isq ? qbih : sbih;
  const float* bhh = isq ? qbhh : sbhh;
  float* xp = isq ? xpq : xps;
  #pragma unroll
  for (int k=0;k<16;k++) wl[k*256+tid] = wih[k*256+tid];
  if (tid < 128) bl[tid] = bih[tid] + bhh[tid];
  __syncthreads();
  const int v = blockIdx.x*256 + tid;
  if (v >= 10000) return;
  float4 e[8];
  #pragma unroll
  for (int q=0;q<8;q++) e[q] = *(const float4*)(emb + v*32 + q*4);
  for (int g=0; g<128; ++g){
    float acc = bl[g];
    #pragma unroll
    for (int q=0;q<8;q++){
      float4 w4 = *(const float4*)(&wl[g*32 + q*4]);
      acc = fmaf(e[q].x, w4.x, acc); acc = fmaf(e[q].y, w4.y, acc);
      acc = fmaf(e[q].z, w4.z, acc); acc = fmaf(e[q].w, w4.w, acc);
    }
    xp[v*128 + (g&15)*8 + (g>>4)] = acc;
  }
}

// ---------------- prep_misc: bf16 weight conversion + tag tables ----------------
__global__ __launch_bounds__(256) void prep_kernel(
    const float* __restrict__ g2w, const float* __restrict__ g3w, const float* __restrict__ g4w,
    const float* __restrict__ g1w,
    const float* __restrict__ swhh, const float* __restrict__ qwhh,
    const float* __restrict__ f1w, const float* __restrict__ f2w, const float* __restrict__ f3w,
    u16* __restrict__ wb,
    u16* __restrict__ wab, u16* __restrict__ wbb,
    float* __restrict__ tga, float* __restrict__ tgb,
    u16* __restrict__ whhbs, u16* __restrict__ whhbq,
    u16* __restrict__ wf1, u16* __restrict__ wf2, u16* __restrict__ wf3)
{
  const int B = 196608;
  const int C = B + 16384;
  const int D = C + 10240;
  const int E = D + 8192;
  const int F = E + 65536;
  const int G = F + 131072;
  const int H = G + 524288;
  for (int idx = blockIdx.x*256 + threadIdx.x; idx < H; idx += gridDim.x*256){
    if (idx < B){
      const int k = idx;
      const float* src = (k < 65536) ? g2w : ((k < 131072) ? g3w : g4w);
      wb[k] = f2bf(src[k & 65535]);
    } else if (idx < C){
      const int k = idx - B;
      if (k < 8192) wab[k] = f2bf(g1w[(k>>5)*136 + (k&31)]);
      else { const int k2 = k - 8192; wbb[k2] = f2bf(g1w[(k2>>5)*136 + 52 + (k2&31)]); }
    } else if (idx < D){
      const int k = idx - C;
      if (k < 5120){ const int s = k >> 8, g = k & 255; tga[k] = g1w[g*136 + 32 + s]; }
      else { const int k2 = k - 5120; const int s = k2 >> 8, g = k2 & 255; tgb[k2] = g1w[g*136 + 84 + s]; }
    } else if (idx < E){
      const int k = idx - D;
      if (k < 4096) whhbs[k] = f2bf(swhh[k]);
      else whhbq[k-4096] = f2bf(qwhh[k-4096]);
    } else if (idx < F){
      const int k = idx - E;
      wf1[k] = f2bf(f1w[k]);
    } else if (idx < G){
      const int k = idx - F;
      wf2[k] = f2bf(f2w[k]);
    } else {
      const int k = idx - G;
      const int o = k >> 9, kk = k & 511;
      wf3[k] = (o < 1000) ? f2bf(f3w[o*512 + kk]) : (u16)0;
    }
  }
}

// ---------------- LSTM via MFMA: 16 sequences per wave ----------------
template<int LEN>
__device__ __forceinline__ void lstm_mfma_run(
    const int* __restrict__ toks, int s0,
    const float* __restrict__ xpr, const u16* __restrict__ whhb,
    u16* __restrict__ hl, int lane, float* h0r, float* h1r)
{
  const int l15 = lane & 15, l4 = lane >> 4;
  short8 wf[8];
  #pragma unroll
  for (int f=0; f<8; f++)
    wf[f] = *(const short8*)(whhb + (f*16+l15)*32 + l4*8);
  short8 ha = (short8){0,0,0,0,0,0,0,0};
  float c0[4] = {0,0,0,0}, c1[4] = {0,0,0,0};
  int tk[4];
  #pragma unroll
  for (int r=0;r<4;r++) tk[r] = toks[(s0 + l4*4 + r)*LEN];
  float4 xa[4], xb[4];
  #pragma unroll
  for (int r=0;r<4;r++){
    xa[r] = *(const float4*)(xpr + tk[r]*128 + l15*8);
    xb[r] = *(const float4*)(xpr + tk[r]*128 + l15*8 + 4);
  }
  #pragma unroll
  for (int t=0; t<LEN; ++t){
    int tkn[4];
    if (t+1 < LEN){
      #pragma unroll
      for (int r=0;r<4;r++) tkn[r] = toks[(s0 + l4*4 + r)*LEN + t + 1];
    }
    const f32x4 z = (f32x4){0.f,0.f,0.f,0.f};
    f32x4 acc[8];
    #pragma unroll
    for (int f=0; f<8; f++)
      acc[f] = __builtin_amdgcn_mfma_f32_16x16x32_bf16(ha, wf[f], z, 0, 0, 0);
    float4 na[4], nb[4];
    if (t+1 < LEN){
      #pragma unroll
      for (int r=0;r<4;r++){
        na[r] = *(const float4*)(xpr + tkn[r]*128 + l15*8);
        nb[r] = *(const float4*)(xpr + tkn[r]*128 + l15*8 + 4);
      }
    }
    #pragma unroll
    for (int r=0;r<4;r++){
      float i0 = sigm(acc[0][r] + xa[r].x);
      float f0 = sigm(acc[2][r] + xa[r].z);
      float g0 = 2.f*sigm(2.f*(acc[4][r] + xb[r].x)) - 1.f;
      float o0 = sigm(acc[6][r] + xb[r].z);
      c0[r] = fmaf(f0, c0[r], i0*g0);
      h0r[r] = o0 * (2.f*sigm(2.f*c0[r]) - 1.f);
      float i1 = sigm(acc[1][r] + xa[r].y);
      float f1v = sigm(acc[3][r] + xa[r].w);
      float g1v = 2.f*sigm(2.f*(acc[5][r] + xb[r].y)) - 1.f;
      float o1 = sigm(acc[7][r] + xb[r].w);
      c1[r] = fmaf(f1v, c1[r], i1*g1v);
      h1r[r] = o1 * (2.f*sigm(2.f*c1[r]) - 1.f);
    }
    if (t+1 < LEN){
      #pragma unroll
      for (int r=0;r<4;r++){
        hl[(l4*4+r)*32 + l15]      = f2bf(h0r[r]);
        hl[(l4*4+r)*32 + 16 + l15] = f2bf(h1r[r]);
      }
      __syncthreads();
      ha = *(const short8*)(hl + l15*32 + l4*8);
      #pragma unroll
      for (int r=0;r<4;r++){ xa[r] = na[r]; xb[r] = nb[r]; }
    }
  }
}

__global__ __launch_bounds__(64) void lstm_kernel(
    const int* __restrict__ story, const int* __restrict__ question,
    const float* __restrict__ xprs, const float* __restrict__ xprq,
    const u16* __restrict__ whhbs, const u16* __restrict__ whhbq,
    u16* __restrict__ stb, float* __restrict__ qst)
{
  __shared__ u16 hl[512];
  const int lane = threadIdx.x;
  const int w = blockIdx.x;
  const int l15 = lane & 15, l4 = lane >> 4;
  float h0r[4], h1r[4];
  if (w >= 640){
    const int s0 = (w - 640)*16;
    lstm_mfma_run<16>(question, s0, xprq, whhbq, hl, lane, h0r, h1r);
    #pragma unroll
    for (int r=0;r<4;r++){
      qst[(s0 + l4*4 + r)*32 + l15]      = h0r[r];
      qst[(s0 + l4*4 + r)*32 + 16 + l15] = h1r[r];
    }
  } else {
    const int s0 = w*16;
    lstm_mfma_run<32>(story, s0, xprs, whhbs, hl, lane, h0r, h1r);
    #pragma unroll
    for (int r=0;r<4;r++){
      stb[(s0 + l4*4 + r)*32 + l15]      = f2bf(h0r[r]);
      stb[(s0 + l4*4 + r)*32 + 16 + l15] = f2bf(h1r[r]);
    }
  }
}

// ---------------- qa = q_state @ Wq^T + g1_b ----------------
__global__ __launch_bounds__(256) void qa_kernel(
    const float* __restrict__ qst, const float* __restrict__ g1w,
    const float* __restrict__ g1b, float* __restrict__ qa)
{
  const int idx = blockIdx.x*256 + threadIdx.x;   // 131072
  const int b = idx >> 8, g = idx & 255;
  const float* qs = qst + b*32;
  const float* wr = g1w + g*136 + 104;
  float acc = g1b[g];
  #pragma unroll
  for (int q=0;q<8;q++){
    float4 s4 = *(const float4*)(qs + q*4);
    float4 w4 = *(const float4*)(wr + q*4);
    acc = fmaf(s4.x, w4.x, acc); acc = fmaf(s4.y, w4.y, acc);
    acc = fmaf(s4.z, w4.z, acc); acc = fmaf(s4.w, w4.w, acc);
  }
  qa[idx] = acc;
}

// ---------------- pi / pj via MFMA; qa folded into pi ----------------
__global__ __launch_bounds__(256) void pipj_kernel(
    const u16* __restrict__ stb, const u16* __restrict__ wab, const u16* __restrict__ wbb,
    const float* __restrict__ tga, const float* __restrict__ tgb,
    const float* __restrict__ qa,
    float* __restrict__ pi, float* __restrict__ pj)
{
  const int tid = threadIdx.x;
  const int lane = tid & 63;
  const int wv = tid >> 6;
  const int l15 = lane & 15;
  const int l4 = lane >> 4;
  const int bs0 = blockIdx.x * 64;
  const bool isj = blockIdx.y;
  const u16* wB = isj ? wbb : wab;
  const float* tg = isj ? tgb : tga;
  float* out = isj ? pj : pi;

  short8 af[4], bf[4];
  #pragma unroll
  for (int mf=0; mf<4; mf++)
    af[mf] = *(const short8*)(stb + (bs0 + mf*16 + l15)*32 + l4*8);
  #pragma unroll
  for (int nf=0; nf<4; nf++)
    bf[nf] = *(const short8*)(wB + (wv*64 + nf*16 + l15)*32 + l4*8);

  #pragma unroll
  for (int mf=0; mf<4; mf++){
    #pragma unroll
    for (int nf=0; nf<4; nf++){
      f32x4 acc = (f32x4){0.f,0.f,0.f,0.f};
      acc = __builtin_amdgcn_mfma_f32_16x16x32_bf16(af[mf], bf[nf], acc, 0, 0, 0);
      const int g = wv*64 + nf*16 + l15;
      #pragma unroll
      for (int r=0; r<4; r++){
        const int bs = bs0 + mf*16 + l4*4 + r;
        const int s = bs % 20;
        float v = acc[r] + tg[s*256 + g];
        if (!isj) v += qa[(bs/20)*256 + g];
        out[bs*256 + g] = v;
      }
    }
  }
}

// ---------------- core relational MLP: 1 tile per block, 4 waves ----------------
// grid (512 b, 5 t); X tile bf16 in LDS [80][266].
// LDX=266 -> 133 dwords/row (odd): xf-read bank = (5*l15 + 4*l4 + w) mod 32,
// max 3 lanes/bank (was 8-way at LDX=264). Stage remapped to 16 rows x 4 chunks
// per wave (same bank pattern). LDS = 42560 B -> 3 blocks/CU.
#define LDX 266
__global__ __launch_bounds__(256) void relnet_kernel(
    const float* __restrict__ pi, const float* __restrict__ pj,
    const u16* __restrict__ w2, const u16* __restrict__ w3, const u16* __restrict__ w4,
    const float* __restrict__ b2, const float* __restrict__ b3, const float* __restrict__ b4,
    float* __restrict__ sgp)
{
  __shared__ u16 Xs[80*LDX];
  const int tid = threadIdx.x;
  const int lane = tid & 63;
  const int wv  = tid >> 6;       // 0..3 -> h-range wv*64
  const int b   = blockIdx.x;
  const int t   = blockIdx.y;
  const int l15 = lane & 15;
  const int l4  = lane >> 4;

  const float* pib = pi + b*(20*256);
  const float* pjb = pj + b*(20*256);

  // ---- X1 = relu(pi' + pj) -> LDS bf16  (qa already folded into pi) ----
  // mapping: u -> m = (u>>9)*16 + (u&15), chunk = (u>>4)&31 (8 u16 per chunk)
  #pragma unroll
  for (int it = 0; it < 10; ++it){
    int u  = it*256 + tid;
    int m  = ((u >> 9) << 4) | (u & 15);
    int gq = ((u >> 4) & 31) << 3;
    int R  = t*80 + m;
    int i  = R / 20;
    int j  = R - i*20;
    const float4* pr = (const float4*)(pib + i*256 + gq);
    const float4* qr = (const float4*)(pjb + j*256 + gq);
    uint4 pk;
    {
      float4 a = pr[0], c4 = qr[0];
      pk.x = pack2(fmaxf(a.x+c4.x,0.f), fmaxf(a.y+c4.y,0.f));
      pk.y = pack2(fmaxf(a.z+c4.z,0.f), fmaxf(a.w+c4.w,0.f));
    }
    {
      float4 a = pr[1], c4 = qr[1];
      pk.z = pack2(fmaxf(a.x+c4.x,0.f), fmaxf(a.y+c4.y,0.f));
      pk.w = pack2(fmaxf(a.z+c4.z,0.f), fmaxf(a.w+c4.w,0.f));
    }
    *(uint4*)(&Xs[m*LDX + gq]) = pk;
  }
  __syncthreads();

  const int arow = wv*64 + l15;   // af row base (hf adds 16)

  // ---- layers 1,2 (g2,g3): X <- relu(W X^T + b) in place ----
  for (int lay = 0; lay < 2; ++lay){
    const u16*   W    = lay ? w3 : w2;
    const float* bias = lay ? b3 : b2;
    f32x4 acc[4][5];
    #pragma unroll
    for (int hf=0; hf<4; hf++)
      #pragma unroll
      for (int mf=0; mf<5; mf++)
        acc[hf][mf] = (f32x4){0.f,0.f,0.f,0.f};

    short8 af0[4], af1[4];
    #pragma unroll
    for (int hf=0; hf<4; hf++)
      af0[hf] = *(const short8*)(W + (arow + hf*16)*256 + l4*8);

    #pragma unroll
    for (int kk = 0; kk < 8; ++kk){
      const int kn = (kk < 7) ? kk+1 : 7;
      #pragma unroll
      for (int hf=0; hf<4; hf++)
        af1[hf] = *(const short8*)(W + (arow + hf*16)*256 + kn*32 + l4*8);
      short8 xf[5];
      #pragma unroll
      for (int mf=0; mf<5; mf++)
        xf[mf] = *(const short8*)(&Xs[(mf*16 + l15)*LDX + kk*32 + l4*8]);
      #pragma unroll
      for (int hf=0; hf<4; hf++)
        #pragma unroll
        for (int mf=0; mf<5; mf++)
          acc[hf][mf] = __builtin_amdgcn_mfma_f32_16x16x32_bf16(af0[hf], xf[mf], acc[hf][mf], 0, 0, 0);
      #pragma unroll
      for (int hf=0; hf<4; hf++) af0[hf] = af1[hf];
    }

    __syncthreads();   // all reads of Xs complete
    #pragma unroll
    for (int hf=0; hf<4; hf++){
      int h0 = wv*64 + hf*16 + l4*4;
      float4 bi = *(const float4*)(bias + h0);
      #pragma unroll
      for (int mf=0; mf<5; mf++){
        int m = mf*16 + l15;
        uint2 pk;
        pk.x = pack2(fmaxf(acc[hf][mf][0]+bi.x,0.f), fmaxf(acc[hf][mf][1]+bi.y,0.f));
        pk.y = pack2(fmaxf(acc[hf][mf][2]+bi.z,0.f), fmaxf(acc[hf][mf][3]+bi.w,0.f));
        *(uint2*)(&Xs[m*LDX + h0]) = pk;
      }
    }
    __syncthreads();
  }

  // ---- layer 3 (g4) + column-sum epilogue ----
  {
    f32x4 acc[4][5];
    #pragma unroll
    for (int hf=0; hf<4; hf++)
      #pragma unroll
      for (int mf=0; mf<5; mf++)
        acc[hf][mf] = (f32x4){0.f,0.f,0.f,0.f};

    short8 af0[4], af1[4];
    #pragma unroll
    for (int hf=0; hf<4; hf++)
      af0[hf] = *(const short8*)(w4 + (arow + hf*16)*256 + l4*8);

    #pragma unroll
    for (int kk = 0; kk < 8; ++kk){
      const int kn = (kk < 7) ? kk+1 : 7;
      #pragma unroll
      for (int hf=0; hf<4; hf++)
        af1[hf] = *(const short8*)(w4 + (arow + hf*16)*256 + kn*32 + l4*8);
      short8 xf[5];
      #pragma unroll
      for (int mf=0; mf<5; mf++)
        xf[mf] = *(const short8*)(&Xs[(mf*16 + l15)*LDX + kk*32 + l4*8]);
      #pragma unroll
      for (int hf=0; hf<4; hf++)
        #pragma unroll
        for (int mf=0; mf<5; mf++)
          acc[hf][mf] = __builtin_amdgcn_mfma_f32_16x16x32_bf16(af0[hf], xf[mf], acc[hf][mf], 0, 0, 0);
      #pragma unroll
      for (int hf=0; hf<4; hf++) af0[hf] = af1[hf];
    }

    #pragma unroll
    for (int hf=0; hf<4; hf++){
      int h0 = wv*64 + hf*16 + l4*4;
      float4 bi = *(const float4*)(b4 + h0);
      float s0 = 0.f, s1 = 0.f, s2 = 0.f, s3 = 0.f;
      #pragma unroll
      for (int mf=0; mf<5; mf++){
        s0 += fmaxf(acc[hf][mf][0]+bi.x,0.f);
        s1 += fmaxf(acc[hf][mf][1]+bi.y,0.f);
        s2 += fmaxf(acc[hf][mf][2]+bi.z,0.f);
        s3 += fmaxf(acc[hf][mf][3]+bi.w,0.f);
      }
      float sv[4] = {s0, s1, s2, s3};
      #pragma unroll
      for (int r=0; r<4; r++){
        float v = sv[r];
        v += __shfl_xor(v, 1);
        v += __shfl_xor(v, 2);
        v += __shfl_xor(v, 4);
        v += __shfl_xor(v, 8);
        if (l15 == 0){
          int h = h0 + r;
          // [t][b][h]: block-exclusive 1KB region -> no cross-XCD line sharing
          sgp[t*131072 + b*256 + h] = v;
        }
      }
    }
  }
}

// ---------------- partial-sum reduce -> bf16 [b][256] ----------------
__global__ __launch_bounds__(256) void sgred_kernel(
    const float* __restrict__ sgp, u16* __restrict__ sgb)
{
  const int idx = blockIdx.x*256 + threadIdx.x;  // b*256 + g
  float v = 0.f;
  #pragma unroll
  for (int t=0;t<5;t++) v += sgp[t*131072 + idx];
  sgb[idx] = f2bf(v);
}

// ---------------- fc layers via MFMA (output sliced over blockIdx.y) ----------------
template<int HF, int KK, int OPAD, int OREAL, int MODE>
__global__ __launch_bounds__(256) void fcm_kernel(
    const u16* __restrict__ in, const u16* __restrict__ w,
    const float* __restrict__ bias, void* __restrict__ outp)
{
  const int K = KK*32;
  const int tid = threadIdx.x, lane = tid & 63, wv = tid >> 6;
  const int l15 = lane & 15, l4 = lane >> 4;
  const int b0 = blockIdx.x*16;
  const int of0 = (blockIdx.y*4 + wv)*HF;   // output fragment base
  f32x4 acc[HF];
  #pragma unroll
  for (int hf=0; hf<HF; hf++) acc[hf] = (f32x4){0.f,0.f,0.f,0.f};
  #pragma unroll 4
  for (int kk=0; kk<KK; ++kk){
    short8 xf = *(const short8*)(in + (b0+l15)*K + kk*32 + l4*8);
    #pragma unroll
    for (int hf=0; hf<HF; hf++){
      short8 af = *(const short8*)(w + ((of0+hf)*16 + l15)*K + kk*32 + l4*8);
      acc[hf] = __builtin_amdgcn_mfma_f32_16x16x32_bf16(af, xf, acc[hf], 0, 0, 0);
    }
  }
  const int b = b0 + l15;
  #pragma unroll
  for (int hf=0; hf<HF; hf++){
    const int o0 = (of0+hf)*16 + l4*4;
    float v[4];
    #pragma unroll
    for (int r=0;r<4;r++){
      float bv = (o0+r < OREAL) ? bias[o0+r] : 0.f;
      v[r] = acc[hf][r] + bv;
    }
    if (MODE == 0){
      uint2 pk;
      pk.x = pack2(fmaxf(v[0],0.f), fmaxf(v[1],0.f));
      pk.y = pack2(fmaxf(v[2],0.f), fmaxf(v[3],0.f));
      *(uint2*)((u16*)outp + (size_t)b*OPAD + o0) = pk;
    } else {
      float* of = (float*)outp;
      #pragma unroll
      for (int r=0;r<4;r++)
        if (o0+r < OREAL) of[(size_t)b*OREAL + o0 + r] = v[r];
    }
  }
}

// ---------------- launch ----------------
extern "C" void kernel_launch(void* const* d_in, const int* in_sizes, int n_in,
                              void* d_out, int out_size, void* d_ws, size_t ws_size,
                              hipStream_t stream)
{
  const int*   story    = (const int*)d_in[0];
  const int*   question = (const int*)d_in[1];
  const float* emb   = (const float*)d_in[2];
  const float* s_wih = (const float*)d_in[3];
  const float* s_whh = (const float*)d_in[4];
  const float* s_bih = (const float*)d_in[5];
  const float* s_bhh = (const float*)d_in[6];
  const float* q_wih = (const float*)d_in[7];
  const float* q_whh = (const float*)d_in[8];
  const float* q_bih = (const float*)d_in[9];
  const float* q_bhh = (const float*)d_in[10];
  const float* g1w = (const float*)d_in[11];
  const float* g1b = (const float*)d_in[12];
  const float* g2w = (const float*)d_in[13];
  const float* g2b = (const float*)d_in[14];
  const float* g3w = (const float*)d_in[15];
  const float* g3b = (const float*)d_in[16];
  const float* g4w = (const float*)d_in[17];
  const float* g4b = (const float*)d_in[18];
  const float* f1w = (const float*)d_in[19];
  const float* f1b = (const float*)d_in[20];
  const float* f2w = (const float*)d_in[21];
  const float* f2b = (const float*)d_in[22];
  const float* f3w = (const float*)d_in[23];
  const float* f3b = (const float*)d_in[24];

  float* ws  = (float*)d_ws;
  float* xps = ws + OFF_XPS;
  float* xpq = ws + OFF_XPQ;
  float* qst = ws + OFF_QST;
  float* pi  = ws + OFF_PI;
  float* pj  = ws + OFF_PJ;
  float* qa  = ws + OFF_QA;
  float* tga = ws + OFF_TGA;
  float* tgb = ws + OFF_TGB;
  float* sgp = ws + OFF_SGP;
  u16*   wb    = (u16*)(ws + OFF_WB);
  u16*   w2b   = wb;
  u16*   w3b   = wb + 65536;
  u16*   w4b   = wb + 131072;
  u16*   stb   = (u16*)(ws + OFF_STB);
  u16*   wab   = (u16*)(ws + OFF_WAB);
  u16*   wbb   = (u16*)(ws + OFF_WBB);
  u16*   whhbs = (u16*)(ws + OFF_WHHS);
  u16*   whhbq = (u16*)(ws + OFF_WHHQ);
  u16*   wf1   = (u16*)(ws + OFF_WF1);
  u16*   wf2   = (u16*)(ws + OFF_WF2);
  u16*   wf3   = (u16*)(ws + OFF_WF3);
  u16*   sgb   = (u16*)(ws + OFF_SGB);
  u16*   act1  = (u16*)(ws + OFF_ACT1);
  u16*   act2  = (u16*)(ws + OFF_ACT2);

  prep_xp_kernel<<<dim3(40,2), dim3(256), 0, stream>>>(
      emb, s_wih, s_bih, s_bhh, q_wih, q_bih, q_bhh, xps, xpq);
  prep_kernel<<<dim3(1024), dim3(256), 0, stream>>>(
      g2w, g3w, g4w, g1w, s_whh, q_whh, f1w, f2w, f3w,
      wb, wab, wbb, tga, tgb, whhbs, whhbq, wf1, wf2, wf3);
  lstm_kernel<<<dim3(672), dim3(64), 0, stream>>>(
      story, question, xps, xpq, whhbs, whhbq, stb, qst);
  qa_kernel<<<dim3(512), dim3(256), 0, stream>>>(qst, g1w, g1b, qa);
  pipj_kernel<<<dim3(160,2), dim3(256), 0, stream>>>(
      stb, wab, wbb, tga, tgb, qa, pi, pj);
  relnet_kernel<<<dim3(512,5), dim3(256), 0, stream>>>(
      pi, pj, w2b, w3b, w4b, g2b, g3b, g4b, sgp);
  sgred_kernel<<<dim3(512), dim3(256), 0, stream>>>(sgp, sgb);
  fcm_kernel<1,8,256,256,0><<<dim3(32,4), dim3(256), 0, stream>>>(sgb, wf1, f1b, act1);
  fcm_kernel<2,8,512,512,0><<<dim3(32,4), dim3(256), 0, stream>>>(act1, wf2, f2b, act2);
  fcm_kernel<2,16,1024,1000,1><<<dim3(32,8), dim3(256), 0, stream>>>(act2, wf3, f3b, (float*)d_out);
}

// Round 10
// 271.379 us; speedup vs baseline: 1.1413x; 1.1413x over previous
//
#include <hip/hip_runtime.h>

typedef unsigned short u16;
typedef unsigned int   u32;
typedef __attribute__((ext_vector_type(8))) short short8;
typedef __attribute__((ext_vector_type(4))) float f32x4;

// ---------------- ws layout (float element offsets) ----------------
#define OFF_XPS   0            // 10000*128 (gate-permuted xp story)
#define OFF_XPQ   1280000      // 10000*128 (gate-permuted xp question)
#define OFF_QST   2560000      // 512*32
#define OFF_PI    2576384      // 512*20*256
#define OFF_PJ    5197824      // 512*20*256
#define OFF_QA    7819264      // 512*256
#define OFF_TGA   7950336      // 20*256
#define OFF_TGB   7955456      // 20*256
#define OFF_WB    7960576      // u16 x 196608 (g2/g3/g4 bf16)
#define OFF_STB   8058880      // u16 x 327680 (story h bf16)
#define OFF_WAB   8222720      // u16 x 8192
#define OFF_WBB   8226816      // u16 x 8192
#define OFF_WHHS  8230912      // u16 x 4096
#define OFF_WHHQ  8232960      // u16 x 4096
#define OFF_WF1   8235008      // u16 x 65536
#define OFF_WF2   8267776      // u16 x 131072
#define OFF_WF3   8333312      // u16 x 524288 (1024x512, zero-padded)
// aliased into XPS/XPQ region (dead after lstm):
#define OFF_SGP   0            // 5*256*512 fl  [t][b][h]
#define OFF_SGB   655360       // u16 x 131072 (sum_g bf16 [b][256])
#define OFF_ACT1  720896       // u16 x 131072 ([b][256])
#define OFF_ACT2  786432       // u16 x 262144 ([b][512])

__device__ __forceinline__ u16 f2bf(float f){
  union { float f; u32 u; } v; v.f = f;
  u32 u = v.u;
  u32 r = u + 0x7fffu + ((u >> 16) & 1u);
  return (u16)(r >> 16);
}
__device__ __forceinline__ u32 pack2(float a, float b){
  u32 r;
  asm("v_cvt_pk_bf16_f32 %0, %1, %2" : "=v"(r) : "v"(a), "v"(b));
  return r;
}
__device__ __forceinline__ float sigm(float x){
  return __builtin_amdgcn_rcpf(1.f + __expf(-x));
}

// ---------------- prep_xp: xp[v][g] tables, W staged in LDS ----------------
__global__ __launch_bounds__(256) void prep_xp_kernel(
    const float* __restrict__ emb,
    const float* __restrict__ swih, const float* __restrict__ sbih, const float* __restrict__ sbhh,
    const float* __restrict__ qwih, const float* __restrict__ qbih, const float* __restrict__ qbhh,
    float* __restrict__ xps, float* __restrict__ xpq)
{
  __shared__ float wl[4096];
  __shared__ float bl[128];
  const int tid = threadIdx.x;
  const bool isq = blockIdx.y;
  const float* wih = isq ? qwih : swih;
  const float* bih = isq ? qbih : sbih;
  const float* bhh = isq ? qbhh : sbhh;
  float* xp = isq ? xpq : xps;
  #pragma unroll
  for (int k=0;k<16;k++) wl[k*256+tid] = wih[k*256+tid];
  if (tid < 128) bl[tid] = bih[tid] + bhh[tid];
  __syncthreads();
  const int v = blockIdx.x*256 + tid;
  if (v >= 10000) return;
  float4 e[8];
  #pragma unroll
  for (int q=0;q<8;q++) e[q] = *(const float4*)(emb + v*32 + q*4);
  for (int g=0; g<128; ++g){
    float acc = bl[g];
    #pragma unroll
    for (int q=0;q<8;q++){
      float4 w4 = *(const float4*)(&wl[g*32 + q*4]);
      acc = fmaf(e[q].x, w4.x, acc); acc = fmaf(e[q].y, w4.y, acc);
      acc = fmaf(e[q].z, w4.z, acc); acc = fmaf(e[q].w, w4.w, acc);
    }
    xp[v*128 + (g&15)*8 + (g>>4)] = acc;
  }
}

// ---------------- prep_misc: bf16 weight conversion + tag tables ----------------
__global__ __launch_bounds__(256) void prep_kernel(
    const float* __restrict__ g2w, const float* __restrict__ g3w, const float* __restrict__ g4w,
    const float* __restrict__ g1w,
    const float* __restrict__ swhh, const float* __restrict__ qwhh,
    const float* __restrict__ f1w, const float* __restrict__ f2w, const float* __restrict__ f3w,
    u16* __restrict__ wb,
    u16* __restrict__ wab, u16* __restrict__ wbb,
    float* __restrict__ tga, float* __restrict__ tgb,
    u16* __restrict__ whhbs, u16* __restrict__ whhbq,
    u16* __restrict__ wf1, u16* __restrict__ wf2, u16* __restrict__ wf3)
{
  const int B = 196608;
  const int C = B + 16384;
  const int D = C + 10240;
  const int E = D + 8192;
  const int F = E + 65536;
  const int G = F + 131072;
  const int H = G + 524288;
  for (int idx = blockIdx.x*256 + threadIdx.x; idx < H; idx += gridDim.x*256){
    if (idx < B){
      const int k = idx;
      const float* src = (k < 65536) ? g2w : ((k < 131072) ? g3w : g4w);
      wb[k] = f2bf(src[k & 65535]);
    } else if (idx < C){
      const int k = idx - B;
      if (k < 8192) wab[k] = f2bf(g1w[(k>>5)*136 + (k&31)]);
      else { const int k2 = k - 8192; wbb[k2] = f2bf(g1w[(k2>>5)*136 + 52 + (k2&31)]); }
    } else if (idx < D){
      const int k = idx - C;
      if (k < 5120){ const int s = k >> 8, g = k & 255; tga[k] = g1w[g*136 + 32 + s]; }
      else { const int k2 = k - 5120; const int s = k2 >> 8, g = k2 & 255; tgb[k2] = g1w[g*136 + 84 + s]; }
    } else if (idx < E){
      const int k = idx - D;
      if (k < 4096) whhbs[k] = f2bf(swhh[k]);
      else whhbq[k-4096] = f2bf(qwhh[k-4096]);
    } else if (idx < F){
      const int k = idx - E;
      wf1[k] = f2bf(f1w[k]);
    } else if (idx < G){
      const int k = idx - F;
      wf2[k] = f2bf(f2w[k]);
    } else {
      const int k = idx - G;
      const int o = k >> 9, kk = k & 511;
      wf3[k] = (o < 1000) ? f2bf(f3w[o*512 + kk]) : (u16)0;
    }
  }
}

// ---------------- LSTM via MFMA: 16 sequences per wave ----------------
template<int LEN>
__device__ __forceinline__ void lstm_mfma_run(
    const int* __restrict__ toks, int s0,
    const float* __restrict__ xpr, const u16* __restrict__ whhb,
    u16* __restrict__ hl, int lane, float* h0r, float* h1r)
{
  const int l15 = lane & 15, l4 = lane >> 4;
  short8 wf[8];
  #pragma unroll
  for (int f=0; f<8; f++)
    wf[f] = *(const short8*)(whhb + (f*16+l15)*32 + l4*8);
  short8 ha = (short8){0,0,0,0,0,0,0,0};
  float c0[4] = {0,0,0,0}, c1[4] = {0,0,0,0};
  int tk[4];
  #pragma unroll
  for (int r=0;r<4;r++) tk[r] = toks[(s0 + l4*4 + r)*LEN];
  float4 xa[4], xb[4];
  #pragma unroll
  for (int r=0;r<4;r++){
    xa[r] = *(const float4*)(xpr + tk[r]*128 + l15*8);
    xb[r] = *(const float4*)(xpr + tk[r]*128 + l15*8 + 4);
  }
  #pragma unroll
  for (int t=0; t<LEN; ++t){
    int tkn[4];
    if (t+1 < LEN){
      #pragma unroll
      for (int r=0;r<4;r++) tkn[r] = toks[(s0 + l4*4 + r)*LEN + t + 1];
    }
    const f32x4 z = (f32x4){0.f,0.f,0.f,0.f};
    f32x4 acc[8];
    #pragma unroll
    for (int f=0; f<8; f++)
      acc[f] = __builtin_amdgcn_mfma_f32_16x16x32_bf16(ha, wf[f], z, 0, 0, 0);
    float4 na[4], nb[4];
    if (t+1 < LEN){
      #pragma unroll
      for (int r=0;r<4;r++){
        na[r] = *(const float4*)(xpr + tkn[r]*128 + l15*8);
        nb[r] = *(const float4*)(xpr + tkn[r]*128 + l15*8 + 4);
      }
    }
    #pragma unroll
    for (int r=0;r<4;r++){
      float i0 = sigm(acc[0][r] + xa[r].x);
      float f0 = sigm(acc[2][r] + xa[r].z);
      float g0 = 2.f*sigm(2.f*(acc[4][r] + xb[r].x)) - 1.f;
      float o0 = sigm(acc[6][r] + xb[r].z);
      c0[r] = fmaf(f0, c0[r], i0*g0);
      h0r[r] = o0 * (2.f*sigm(2.f*c0[r]) - 1.f);
      float i1 = sigm(acc[1][r] + xa[r].y);
      float f1v = sigm(acc[3][r] + xa[r].w);
      float g1v = 2.f*sigm(2.f*(acc[5][r] + xb[r].y)) - 1.f;
      float o1 = sigm(acc[7][r] + xb[r].w);
      c1[r] = fmaf(f1v, c1[r], i1*g1v);
      h1r[r] = o1 * (2.f*sigm(2.f*c1[r]) - 1.f);
    }
    if (t+1 < LEN){
      #pragma unroll
      for (int r=0;r<4;r++){
        hl[(l4*4+r)*32 + l15]      = f2bf(h0r[r]);
        hl[(l4*4+r)*32 + 16 + l15] = f2bf(h1r[r]);
      }
      __syncthreads();
      ha = *(const short8*)(hl + l15*32 + l4*8);
      #pragma unroll
      for (int r=0;r<4;r++){ xa[r] = na[r]; xb[r] = nb[r]; }
    }
  }
}

__global__ __launch_bounds__(64) void lstm_kernel(
    const int* __restrict__ story, const int* __restrict__ question,
    const float* __restrict__ xprs, const float* __restrict__ xprq,
    const u16* __restrict__ whhbs, const u16* __restrict__ whhbq,
    u16* __restrict__ stb, float* __restrict__ qst)
{
  __shared__ u16 hl[512];
  const int lane = threadIdx.x;
  const int w = blockIdx.x;
  const int l15 = lane & 15, l4 = lane >> 4;
  float h0r[4], h1r[4];
  if (w >= 640){
    const int s0 = (w - 640)*16;
    lstm_mfma_run<16>(question, s0, xprq, whhbq, hl, lane, h0r, h1r);
    #pragma unroll
    for (int r=0;r<4;r++){
      qst[(s0 + l4*4 + r)*32 + l15]      = h0r[r];
      qst[(s0 + l4*4 + r)*32 + 16 + l15] = h1r[r];
    }
  } else {
    const int s0 = w*16;
    lstm_mfma_run<32>(story, s0, xprs, whhbs, hl, lane, h0r, h1r);
    #pragma unroll
    for (int r=0;r<4;r++){
      stb[(s0 + l4*4 + r)*32 + l15]      = f2bf(h0r[r]);
      stb[(s0 + l4*4 + r)*32 + 16 + l15] = f2bf(h1r[r]);
    }
  }
}

// ---------------- pi / pj via MFMA (K=32, one step); y==2 computes qa ----------------
__global__ __launch_bounds__(256) void pipj_kernel(
    const u16* __restrict__ stb, const u16* __restrict__ wab, const u16* __restrict__ wbb,
    const float* __restrict__ tga, const float* __restrict__ tgb,
    const float* __restrict__ qst, const float* __restrict__ g1w, const float* __restrict__ g1b,
    float* __restrict__ pi, float* __restrict__ pj, float* __restrict__ qa)
{
  const int tid = threadIdx.x;
  if (blockIdx.y == 2){
    for (int idx = blockIdx.x*256 + tid; idx < 131072; idx += 160*256){
      const int b = idx >> 8, g = idx & 255;
      const float* qs = qst + b*32;
      const float* wr = g1w + g*136 + 104;
      float acc = g1b[g];
      #pragma unroll
      for (int q=0;q<8;q++){
        float4 s4 = *(const float4*)(qs + q*4);
        float4 w4 = *(const float4*)(wr + q*4);
        acc = fmaf(s4.x, w4.x, acc); acc = fmaf(s4.y, w4.y, acc);
        acc = fmaf(s4.z, w4.z, acc); acc = fmaf(s4.w, w4.w, acc);
      }
      qa[idx] = acc;
    }
    return;
  }
  const int lane = tid & 63;
  const int wv = tid >> 6;
  const int l15 = lane & 15;
  const int l4 = tid >> 4 & 3;
  const int l4r = lane >> 4;
  const int bs0 = blockIdx.x * 64;
  const bool isj = blockIdx.y;
  const u16* wB = isj ? wbb : wab;
  const float* tg = isj ? tgb : tga;
  float* out = isj ? pj : pi;

  short8 af[4], bf[4];
  #pragma unroll
  for (int mf=0; mf<4; mf++)
    af[mf] = *(const short8*)(stb + (bs0 + mf*16 + l15)*32 + l4r*8);
  #pragma unroll
  for (int nf=0; nf<4; nf++)
    bf[nf] = *(const short8*)(wB + (wv*64 + nf*16 + l15)*32 + l4r*8);

  #pragma unroll
  for (int mf=0; mf<4; mf++){
    #pragma unroll
    for (int nf=0; nf<4; nf++){
      f32x4 acc = (f32x4){0.f,0.f,0.f,0.f};
      acc = __builtin_amdgcn_mfma_f32_16x16x32_bf16(af[mf], bf[nf], acc, 0, 0, 0);
      const int g = wv*64 + nf*16 + l15;
      #pragma unroll
      for (int r=0; r<4; r++){
        const int bs = bs0 + mf*16 + l4r*4 + r;
        const int s = bs % 20;
        out[bs*256 + g] = acc[r] + tg[s*256 + g];
      }
    }
  }
}

// ---------------- core relational MLP: 2-wave blocks, wave owns 128 h ----------------
// grid (512 b, 5 t) x 128 threads; X tile bf16 in LDS [80][264].
// Halves per-CU LDS-read duplication vs 4-wave h64 (each wave reads full X per layer).
// acc[8][5] ~160 regs -> unified VGPR/AGPR, 2-wave/SIMD bucket (<=256).
#define LDX 264
__global__ __launch_bounds__(128) void relnet_kernel(
    const float* __restrict__ pi, const float* __restrict__ pj, const float* __restrict__ qa,
    const u16* __restrict__ w2, const u16* __restrict__ w3, const u16* __restrict__ w4,
    const float* __restrict__ b2, const float* __restrict__ b3, const float* __restrict__ b4,
    float* __restrict__ sgp)
{
  __shared__ u16 Xs[80*LDX];
  const int tid = threadIdx.x;
  const int lane = tid & 63;
  const int wv  = tid >> 6;       // 0..1 -> h-range wv*128
  const int b   = blockIdx.x;
  const int t   = blockIdx.y;
  const int l15 = lane & 15;
  const int l4  = lane >> 4;

  const float* pib = pi + b*(20*256);
  const float* pjb = pj + b*(20*256);
  const float* qab = qa + b*256;

  // ---- X1 = relu(pi + pj + qa) -> LDS bf16 ----
  #pragma unroll
  for (int it = 0; it < 20; ++it){
    int u  = it*128 + tid;
    int m  = u >> 5;
    int gq = (u & 31) << 3;
    int R  = t*80 + m;
    int i  = R / 20;
    int j  = R - i*20;
    const float4* pr = (const float4*)(pib + i*256 + gq);
    const float4* qr = (const float4*)(pjb + j*256 + gq);
    const float4* ar = (const float4*)(qab + gq);
    uint4 pk;
    {
      float4 a = pr[0], c4 = qr[0], d4 = ar[0];
      pk.x = pack2(fmaxf(a.x+c4.x+d4.x,0.f), fmaxf(a.y+c4.y+d4.y,0.f));
      pk.y = pack2(fmaxf(a.z+c4.z+d4.z,0.f), fmaxf(a.w+c4.w+d4.w,0.f));
    }
    {
      float4 a = pr[1], c4 = qr[1], d4 = ar[1];
      pk.z = pack2(fmaxf(a.x+c4.x+d4.x,0.f), fmaxf(a.y+c4.y+d4.y,0.f));
      pk.w = pack2(fmaxf(a.z+c4.z+d4.z,0.f), fmaxf(a.w+c4.w+d4.w,0.f));
    }
    *(uint4*)(&Xs[m*LDX + gq]) = pk;
  }
  __syncthreads();

  // ---- layers 1,2 (g2,g3): X <- relu(W X^T + b) in place ----
  for (int lay = 0; lay < 2; ++lay){
    const u16*   W    = lay ? w3 : w2;
    const float* bias = lay ? b3 : b2;
    f32x4 acc[8][5];
    #pragma unroll
    for (int hf=0; hf<8; hf++)
      #pragma unroll
      for (int mf=0; mf<5; mf++)
        acc[hf][mf] = (f32x4){0.f,0.f,0.f,0.f};

    #pragma unroll
    for (int kk = 0; kk < 8; ++kk){
      short8 af[8], xf[5];
      #pragma unroll
      for (int hf=0; hf<8; hf++){
        int row = wv*128 + hf*16 + l15;
        af[hf] = *(const short8*)(W + row*256 + kk*32 + l4*8);
      }
      #pragma unroll
      for (int mf=0; mf<5; mf++)
        xf[mf] = *(const short8*)(&Xs[(mf*16 + l15)*LDX + kk*32 + l4*8]);
      #pragma unroll
      for (int hf=0; hf<8; hf++)
        #pragma unroll
        for (int mf=0; mf<5; mf++)
          acc[hf][mf] = __builtin_amdgcn_mfma_f32_16x16x32_bf16(af[hf], xf[mf], acc[hf][mf], 0, 0, 0);
    }

    __syncthreads();   // all reads of Xs complete
    #pragma unroll
    for (int hf=0; hf<8; hf++){
      int h0 = wv*128 + hf*16 + l4*4;
      float4 bi = *(const float4*)(bias + h0);
      #pragma unroll
      for (int mf=0; mf<5; mf++){
        int m = mf*16 + l15;
        uint2 pk;
        pk.x = pack2(fmaxf(acc[hf][mf][0]+bi.x,0.f), fmaxf(acc[hf][mf][1]+bi.y,0.f));
        pk.y = pack2(fmaxf(acc[hf][mf][2]+bi.z,0.f), fmaxf(acc[hf][mf][3]+bi.w,0.f));
        *(uint2*)(&Xs[m*LDX + h0]) = pk;
      }
    }
    __syncthreads();
  }

  // ---- layer 3 (g4) + column-sum epilogue ----
  {
    f32x4 acc[8][5];
    #pragma unroll
    for (int hf=0; hf<8; hf++)
      #pragma unroll
      for (int mf=0; mf<5; mf++)
        acc[hf][mf] = (f32x4){0.f,0.f,0.f,0.f};

    #pragma unroll
    for (int kk = 0; kk < 8; ++kk){
      short8 af[8], xf[5];
      #pragma unroll
      for (int hf=0; hf<8; hf++){
        int row = wv*128 + hf*16 + l15;
        af[hf] = *(const short8*)(w4 + row*256 + kk*32 + l4*8);
      }
      #pragma unroll
      for (int mf=0; mf<5; mf++)
        xf[mf] = *(const short8*)(&Xs[(mf*16 + l15)*LDX + kk*32 + l4*8]);
      #pragma unroll
      for (int hf=0; hf<8; hf++)
        #pragma unroll
        for (int mf=0; mf<5; mf++)
          acc[hf][mf] = __builtin_amdgcn_mfma_f32_16x16x32_bf16(af[hf], xf[mf], acc[hf][mf], 0, 0, 0);
    }

    #pragma unroll
    for (int hf=0; hf<8; hf++){
      int h0 = wv*128 + hf*16 + l4*4;
      float4 bi = *(const float4*)(b4 + h0);
      float s0 = 0.f, s1 = 0.f, s2 = 0.f, s3 = 0.f;
      #pragma unroll
      for (int mf=0; mf<5; mf++){
        s0 += fmaxf(acc[hf][mf][0]+bi.x,0.f);
        s1 += fmaxf(acc[hf][mf][1]+bi.y,0.f);
        s2 += fmaxf(acc[hf][mf][2]+bi.z,0.f);
        s3 += fmaxf(acc[hf][mf][3]+bi.w,0.f);
      }
      float sv[4] = {s0, s1, s2, s3};
      #pragma unroll
      for (int r=0; r<4; r++){
        float v = sv[r];
        v += __shfl_xor(v, 1);
        v += __shfl_xor(v, 2);
        v += __shfl_xor(v, 4);
        v += __shfl_xor(v, 8);
        if (l15 == 0){
          int h = h0 + r;
          // [t][b][h]: block-exclusive region -> no cross-XCD false sharing
          sgp[t*131072 + b*256 + h] = v;
        }
      }
    }
  }
}

// ---------------- partial-sum reduce -> bf16 [b][256] ----------------
__global__ __launch_bounds__(256) void sgred_kernel(
    const float* __restrict__ sgp, u16* __restrict__ sgb)
{
  const int idx = blockIdx.x*256 + threadIdx.x;  // b*256 + g
  float v = 0.f;
  #pragma unroll
  for (int t=0;t<5;t++) v += sgp[t*131072 + idx];
  sgb[idx] = f2bf(v);
}

// ---------------- fc layers via MFMA (output sliced over blockIdx.y) ----------------
template<int HF, int KK, int OPAD, int OREAL, int MODE>
__global__ __launch_bounds__(256) void fcm_kernel(
    const u16* __restrict__ in, const u16* __restrict__ w,
    const float* __restrict__ bias, void* __restrict__ outp)
{
  const int K = KK*32;
  const int tid = threadIdx.x, lane = tid & 63, wv = tid >> 6;
  const int l15 = lane & 15, l4 = lane >> 4;
  const int b0 = blockIdx.x*16;
  const int of0 = (blockIdx.y*4 + wv)*HF;   // output fragment base
  f32x4 acc[HF];
  #pragma unroll
  for (int hf=0; hf<HF; hf++) acc[hf] = (f32x4){0.f,0.f,0.f,0.f};
  #pragma unroll 4
  for (int kk=0; kk<KK; ++kk){
    short8 xf = *(const short8*)(in + (b0+l15)*K + kk*32 + l4*8);
    #pragma unroll
    for (int hf=0; hf<HF; hf++){
      short8 af = *(const short8*)(w + ((of0+hf)*16 + l15)*K + kk*32 + l4*8);
      acc[hf] = __builtin_amdgcn_mfma_f32_16x16x32_bf16(af, xf, acc[hf], 0, 0, 0);
    }
  }
  const int b = b0 + l15;
  #pragma unroll
  for (int hf=0; hf<HF; hf++){
    const int o0 = (of0+hf)*16 + l4*4;
    float v[4];
    #pragma unroll
    for (int r=0;r<4;r++){
      float bv = (o0+r < OREAL) ? bias[o0+r] : 0.f;
      v[r] = acc[hf][r] + bv;
    }
    if (MODE == 0){
      uint2 pk;
      pk.x = pack2(fmaxf(v[0],0.f), fmaxf(v[1],0.f));
      pk.y = pack2(fmaxf(v[2],0.f), fmaxf(v[3],0.f));
      *(uint2*)((u16*)outp + (size_t)b*OPAD + o0) = pk;
    } else {
      float* of = (float*)outp;
      #pragma unroll
      for (int r=0;r<4;r++)
        if (o0+r < OREAL) of[(size_t)b*OREAL + o0 + r] = v[r];
    }
  }
}

// ---------------- launch ----------------
extern "C" void kernel_launch(void* const* d_in, const int* in_sizes, int n_in,
                              void* d_out, int out_size, void* d_ws, size_t ws_size,
                              hipStream_t stream)
{
  const int*   story    = (const int*)d_in[0];
  const int*   question = (const int*)d_in[1];
  const float* emb   = (const float*)d_in[2];
  const float* s_wih = (const float*)d_in[3];
  const float* s_whh = (const float*)d_in[4];
  const float* s_bih = (const float*)d_in[5];
  const float* s_bhh = (const float*)d_in[6];
  const float* q_wih = (const float*)d_in[7];
  const float* q_whh = (const float*)d_in[8];
  const float* q_bih = (const float*)d_in[9];
  const float* q_bhh = (const float*)d_in[10];
  const float* g1w = (const float*)d_in[11];
  const float* g1b = (const float*)d_in[12];
  const float* g2w = (const float*)d_in[13];
  const float* g2b = (const float*)d_in[14];
  const float* g3w = (const float*)d_in[15];
  const float* g3b = (const float*)d_in[16];
  const float* g4w = (const float*)d_in[17];
  const float* g4b = (const float*)d_in[18];
  const float* f1w = (const float*)d_in[19];
  const float* f1b = (const float*)d_in[20];
  const float* f2w = (const float*)d_in[21];
  const float* f2b = (const float*)d_in[22];
  const float* f3w = (const float*)d_in[23];
  const float* f3b = (const float*)d_in[24];

  float* ws  = (float*)d_ws;
  float* xps = ws + OFF_XPS;
  float* xpq = ws + OFF_XPQ;
  float* qst = ws + OFF_QST;
  float* pi  = ws + OFF_PI;
  float* pj  = ws + OFF_PJ;
  float* qa  = ws + OFF_QA;
  float* tga = ws + OFF_TGA;
  float* tgb = ws + OFF_TGB;
  float* sgp = ws + OFF_SGP;
  u16*   wb    = (u16*)(ws + OFF_WB);
  u16*   w2b   = wb;
  u16*   w3b   = wb + 65536;
  u16*   w4b   = wb + 131072;
  u16*   stb   = (u16*)(ws + OFF_STB);
  u16*   wab   = (u16*)(ws + OFF_WAB);
  u16*   wbb   = (u16*)(ws + OFF_WBB);
  u16*   whhbs = (u16*)(ws + OFF_WHHS);
  u16*   whhbq = (u16*)(ws + OFF_WHHQ);
  u16*   wf1   = (u16*)(ws + OFF_WF1);
  u16*   wf2   = (u16*)(ws + OFF_WF2);
  u16*   wf3   = (u16*)(ws + OFF_WF3);
  u16*   sgb   = (u16*)(ws + OFF_SGB);
  u16*   act1  = (u16*)(ws + OFF_ACT1);
  u16*   act2  = (u16*)(ws + OFF_ACT2);

  prep_xp_kernel<<<dim3(40,2), dim3(256), 0, stream>>>(
      emb, s_wih, s_bih, s_bhh, q_wih, q_bih, q_bhh, xps, xpq);
  prep_kernel<<<dim3(1024), dim3(256), 0, stream>>>(
      g2w, g3w, g4w, g1w, s_whh, q_whh, f1w, f2w, f3w,
      wb, wab, wbb, tga, tgb, whhbs, whhbq, wf1, wf2, wf3);
  lstm_kernel<<<dim3(672), dim3(64), 0, stream>>>(
      story, question, xps, xpq, whhbs, whhbq, stb, qst);
  pipj_kernel<<<dim3(160,3), dim3(256), 0, stream>>>(
      stb, wab, wbb, tga, tgb, qst, g1w, g1b, pi, pj, qa);
  relnet_kernel<<<dim3(512,5), dim3(128), 0, stream>>>(
      pi, pj, qa, w2b, w3b, w4b, g2b, g3b, g4b, sgp);
  sgred_kernel<<<dim3(512), dim3(256), 0, stream>>>(sgp, sgb);
  fcm_kernel<1,8,256,256,0><<<dim3(32,4), dim3(256), 0, stream>>>(sgb, wf1, f1b, act1);
  fcm_kernel<2,8,512,512,0><<<dim3(32,4), dim3(256), 0, stream>>>(act1, wf2, f2b, act2);
  fcm_kernel<2,16,1024,1000,1><<<dim3(32,8), dim3(256), 0, stream>>>(act2, wf3, f3b, (float*)d_out);
}

// Round 11
// 244.184 us; speedup vs baseline: 1.2684x; 1.1114x over previous
//
#include <hip/hip_runtime.h>

typedef unsigned short u16;
typedef unsigned int   u32;
typedef __attribute__((ext_vector_type(8))) short short8;
typedef __attribute__((ext_vector_type(4))) float f32x4;

// ---------------- ws layout (float element offsets) ----------------
#define OFF_XPS   0            // 10000*128 (gate-permuted xp story)
#define OFF_XPQ   1280000      // 10000*128 (gate-permuted xp question)
#define OFF_QST   2560000      // 512*32
#define OFF_PI    2576384      // 512*20*256
#define OFF_PJ    5197824      // 512*20*256
#define OFF_QA    7819264      // 512*256
#define OFF_TGA   7950336      // 20*256
#define OFF_TGB   7955456      // 20*256
#define OFF_WB    7960576      // u16 x 196608 (g2/g3/g4 bf16)
#define OFF_STB   8058880      // u16 x 327680 (story h bf16)
#define OFF_WAB   8222720      // u16 x 8192
#define OFF_WBB   8226816      // u16 x 8192
#define OFF_WHHS  8230912      // u16 x 4096
#define OFF_WHHQ  8232960      // u16 x 4096
#define OFF_WF1   8235008      // u16 x 65536
#define OFF_WF2   8267776      // u16 x 131072
#define OFF_WF3   8333312      // u16 x 524288 (1024x512, zero-padded)
// aliased into XPS/XPQ region (dead after lstm):
#define OFF_SGP   0            // 5*256*512 fl  [t][b][h]
#define OFF_ACT1  720896       // u16 x 131072 ([b][256])
#define OFF_ACT2  786432       // u16 x 262144 ([b][512])

__device__ __forceinline__ u16 f2bf(float f){
  union { float f; u32 u; } v; v.f = f;
  u32 u = v.u;
  u32 r = u + 0x7fffu + ((u >> 16) & 1u);
  return (u16)(r >> 16);
}
__device__ __forceinline__ u32 pack2(float a, float b){
  u32 r;
  asm("v_cvt_pk_bf16_f32 %0, %1, %2" : "=v"(r) : "v"(a), "v"(b));
  return r;
}
__device__ __forceinline__ float sigm(float x){
  return __builtin_amdgcn_rcpf(1.f + __expf(-x));
}

// ---------------- prep: xp tables (y=0,1) + misc conversions (y=2) ----------------
__global__ __launch_bounds__(256) void prep_kernel(
    const float* __restrict__ emb,
    const float* __restrict__ swih, const float* __restrict__ sbih, const float* __restrict__ sbhh,
    const float* __restrict__ qwih, const float* __restrict__ qbih, const float* __restrict__ qbhh,
    const float* __restrict__ g2w, const float* __restrict__ g3w, const float* __restrict__ g4w,
    const float* __restrict__ g1w,
    const float* __restrict__ swhh, const float* __restrict__ qwhh,
    const float* __restrict__ f1w, const float* __restrict__ f2w, const float* __restrict__ f3w,
    float* __restrict__ xps, float* __restrict__ xpq,
    u16* __restrict__ wb, u16* __restrict__ wab, u16* __restrict__ wbb,
    float* __restrict__ tga, float* __restrict__ tgb,
    u16* __restrict__ whhbs, u16* __restrict__ whhbq,
    u16* __restrict__ wf1, u16* __restrict__ wf2, u16* __restrict__ wf3)
{
  __shared__ float wl[4096];
  __shared__ float bl[128];
  const int tid = threadIdx.x;
  if (blockIdx.y == 2){
    const int B = 196608;
    const int C = B + 16384;
    const int D = C + 10240;
    const int E = D + 8192;
    const int F = E + 65536;
    const int G = F + 131072;
    const int H = G + 524288;
    for (int idx = blockIdx.x*256 + tid; idx < H; idx += 40*256){
      if (idx < B){
        const int k = idx;
        const float* src = (k < 65536) ? g2w : ((k < 131072) ? g3w : g4w);
        wb[k] = f2bf(src[k & 65535]);
      } else if (idx < C){
        const int k = idx - B;
        if (k < 8192) wab[k] = f2bf(g1w[(k>>5)*136 + (k&31)]);
        else { const int k2 = k - 8192; wbb[k2] = f2bf(g1w[(k2>>5)*136 + 52 + (k2&31)]); }
      } else if (idx < D){
        const int k = idx - C;
        if (k < 5120){ const int s = k >> 8, g = k & 255; tga[k] = g1w[g*136 + 32 + s]; }
        else { const int k2 = k - 5120; const int s = k2 >> 8, g = k2 & 255; tgb[k2] = g1w[g*136 + 84 + s]; }
      } else if (idx < E){
        const int k = idx - D;
        if (k < 4096) whhbs[k] = f2bf(swhh[k]);
        else whhbq[k-4096] = f2bf(qwhh[k-4096]);
      } else if (idx < F){
        const int k = idx - E;
        wf1[k] = f2bf(f1w[k]);
      } else if (idx < G){
        const int k = idx - F;
        wf2[k] = f2bf(f2w[k]);
      } else {
        const int k = idx - G;
        const int o = k >> 9, kk = k & 511;
        wf3[k] = (o < 1000) ? f2bf(f3w[o*512 + kk]) : (u16)0;
      }
    }
    return;
  }
  const bool isq = blockIdx.y;
  const float* wih = isq ? qwih : swih;
  const float* bih = isq ? qbih : sbih;
  const float* bhh = isq ? qbhh : sbhh;
  float* xp = isq ? xpq : xps;
  #pragma unroll
  for (int k=0;k<16;k++) wl[k*256+tid] = wih[k*256+tid];
  if (tid < 128) bl[tid] = bih[tid] + bhh[tid];
  __syncthreads();
  const int v = blockIdx.x*256 + tid;
  if (v >= 10000) return;
  float4 e[8];
  #pragma unroll
  for (int q=0;q<8;q++) e[q] = *(const float4*)(emb + v*32 + q*4);
  for (int g=0; g<128; ++g){
    float acc = bl[g];
    #pragma unroll
    for (int q=0;q<8;q++){
      float4 w4 = *(const float4*)(&wl[g*32 + q*4]);
      acc = fmaf(e[q].x, w4.x, acc); acc = fmaf(e[q].y, w4.y, acc);
      acc = fmaf(e[q].z, w4.z, acc); acc = fmaf(e[q].w, w4.w, acc);
    }
    xp[v*128 + (g&15)*8 + (g>>4)] = acc;
  }
}

// ---------------- LSTM via MFMA: 16 sequences per wave ----------------
template<int LEN>
__device__ __forceinline__ void lstm_mfma_run(
    const int* __restrict__ toks, int s0,
    const float* __restrict__ xpr, const u16* __restrict__ whhb,
    u16* __restrict__ hl, int lane, float* h0r, float* h1r)
{
  const int l15 = lane & 15, l4 = lane >> 4;
  short8 wf[8];
  #pragma unroll
  for (int f=0; f<8; f++)
    wf[f] = *(const short8*)(whhb + (f*16+l15)*32 + l4*8);
  short8 ha = (short8){0,0,0,0,0,0,0,0};
  float c0[4] = {0,0,0,0}, c1[4] = {0,0,0,0};
  int tk[4];
  #pragma unroll
  for (int r=0;r<4;r++) tk[r] = toks[(s0 + l4*4 + r)*LEN];
  float4 xa[4], xb[4];
  #pragma unroll
  for (int r=0;r<4;r++){
    xa[r] = *(const float4*)(xpr + tk[r]*128 + l15*8);
    xb[r] = *(const float4*)(xpr + tk[r]*128 + l15*8 + 4);
  }
  #pragma unroll
  for (int t=0; t<LEN; ++t){
    int tkn[4];
    if (t+1 < LEN){
      #pragma unroll
      for (int r=0;r<4;r++) tkn[r] = toks[(s0 + l4*4 + r)*LEN + t + 1];
    }
    const f32x4 z = (f32x4){0.f,0.f,0.f,0.f};
    f32x4 acc[8];
    #pragma unroll
    for (int f=0; f<8; f++)
      acc[f] = __builtin_amdgcn_mfma_f32_16x16x32_bf16(ha, wf[f], z, 0, 0, 0);
    float4 na[4], nb[4];
    if (t+1 < LEN){
      #pragma unroll
      for (int r=0;r<4;r++){
        na[r] = *(const float4*)(xpr + tkn[r]*128 + l15*8);
        nb[r] = *(const float4*)(xpr + tkn[r]*128 + l15*8 + 4);
      }
    }
    #pragma unroll
    for (int r=0;r<4;r++){
      float i0 = sigm(acc[0][r] + xa[r].x);
      float f0 = sigm(acc[2][r] + xa[r].z);
      float g0 = 2.f*sigm(2.f*(acc[4][r] + xb[r].x)) - 1.f;
      float o0 = sigm(acc[6][r] + xb[r].z);
      c0[r] = fmaf(f0, c0[r], i0*g0);
      h0r[r] = o0 * (2.f*sigm(2.f*c0[r]) - 1.f);
      float i1 = sigm(acc[1][r] + xa[r].y);
      float f1v = sigm(acc[3][r] + xa[r].w);
      float g1v = 2.f*sigm(2.f*(acc[5][r] + xb[r].y)) - 1.f;
      float o1 = sigm(acc[7][r] + xb[r].w);
      c1[r] = fmaf(f1v, c1[r], i1*g1v);
      h1r[r] = o1 * (2.f*sigm(2.f*c1[r]) - 1.f);
    }
    if (t+1 < LEN){
      #pragma unroll
      for (int r=0;r<4;r++){
        hl[(l4*4+r)*32 + l15]      = f2bf(h0r[r]);
        hl[(l4*4+r)*32 + 16 + l15] = f2bf(h1r[r]);
      }
      __syncthreads();
      ha = *(const short8*)(hl + l15*32 + l4*8);
      #pragma unroll
      for (int r=0;r<4;r++){ xa[r] = na[r]; xb[r] = nb[r]; }
    }
  }
}

__global__ __launch_bounds__(64) void lstm_kernel(
    const int* __restrict__ story, const int* __restrict__ question,
    const float* __restrict__ xprs, const float* __restrict__ xprq,
    const u16* __restrict__ whhbs, const u16* __restrict__ whhbq,
    u16* __restrict__ stb, float* __restrict__ qst)
{
  __shared__ u16 hl[512];
  const int lane = threadIdx.x;
  const int w = blockIdx.x;
  const int l15 = lane & 15, l4 = lane >> 4;
  float h0r[4], h1r[4];
  if (w >= 640){
    const int s0 = (w - 640)*16;
    lstm_mfma_run<16>(question, s0, xprq, whhbq, hl, lane, h0r, h1r);
    #pragma unroll
    for (int r=0;r<4;r++){
      qst[(s0 + l4*4 + r)*32 + l15]      = h0r[r];
      qst[(s0 + l4*4 + r)*32 + 16 + l15] = h1r[r];
    }
  } else {
    const int s0 = w*16;
    lstm_mfma_run<32>(story, s0, xprs, whhbs, hl, lane, h0r, h1r);
    #pragma unroll
    for (int r=0;r<4;r++){
      stb[(s0 + l4*4 + r)*32 + l15]      = f2bf(h0r[r]);
      stb[(s0 + l4*4 + r)*32 + 16 + l15] = f2bf(h1r[r]);
    }
  }
}

// ---------------- pi / pj via MFMA (K=32, one step); y==2 computes qa ----------------
__global__ __launch_bounds__(256) void pipj_kernel(
    const u16* __restrict__ stb, const u16* __restrict__ wab, const u16* __restrict__ wbb,
    const float* __restrict__ tga, const float* __restrict__ tgb,
    const float* __restrict__ qst, const float* __restrict__ g1w, const float* __restrict__ g1b,
    float* __restrict__ pi, float* __restrict__ pj, float* __restrict__ qa)
{
  const int tid = threadIdx.x;
  if (blockIdx.y == 2){
    for (int idx = blockIdx.x*256 + tid; idx < 131072; idx += 160*256){
      const int b = idx >> 8, g = idx & 255;
      const float* qs = qst + b*32;
      const float* wr = g1w + g*136 + 104;
      float acc = g1b[g];
      #pragma unroll
      for (int q=0;q<8;q++){
        float4 s4 = *(const float4*)(qs + q*4);
        float4 w4 = *(const float4*)(wr + q*4);
        acc = fmaf(s4.x, w4.x, acc); acc = fmaf(s4.y, w4.y, acc);
        acc = fmaf(s4.z, w4.z, acc); acc = fmaf(s4.w, w4.w, acc);
      }
      qa[idx] = acc;
    }
    return;
  }
  const int lane = tid & 63;
  const int wv = tid >> 6;
  const int l15 = lane & 15;
  const int l4r = lane >> 4;
  const int bs0 = blockIdx.x * 64;
  const bool isj = blockIdx.y;
  const u16* wB = isj ? wbb : wab;
  const float* tg = isj ? tgb : tga;
  float* out = isj ? pj : pi;

  short8 af[4], bf[4];
  #pragma unroll
  for (int mf=0; mf<4; mf++)
    af[mf] = *(const short8*)(stb + (bs0 + mf*16 + l15)*32 + l4r*8);
  #pragma unroll
  for (int nf=0; nf<4; nf++)
    bf[nf] = *(const short8*)(wB + (wv*64 + nf*16 + l15)*32 + l4r*8);

  #pragma unroll
  for (int mf=0; mf<4; mf++){
    #pragma unroll
    for (int nf=0; nf<4; nf++){
      f32x4 acc = (f32x4){0.f,0.f,0.f,0.f};
      acc = __builtin_amdgcn_mfma_f32_16x16x32_bf16(af[mf], bf[nf], acc, 0, 0, 0);
      const int g = wv*64 + nf*16 + l15;
      #pragma unroll
      for (int r=0; r<4; r++){
        const int bs = bs0 + mf*16 + l4r*4 + r;
        const int s = bs % 20;
        out[bs*256 + g] = acc[r] + tg[s*256 + g];
      }
    }
  }
}

// ---------------- core relational MLP: 8-wave blocks, LDS-padded for clean regs ----------------
// grid (512 b, 5 t) x 512 threads; X tile bf16 in LDS [80][264].
// LDS padded to 55.5KB -> 2 blocks/CU -> 4 waves/SIMD -> VGPR cap 128 (live ~90, no spill).
// 16 waves/CU residency = the r5 shape without its spill.
#define LDX 264
__global__ __launch_bounds__(512) void relnet_kernel(
    const float* __restrict__ pi, const float* __restrict__ pj, const float* __restrict__ qa,
    const u16* __restrict__ w2, const u16* __restrict__ w3, const u16* __restrict__ w4,
    const float* __restrict__ b2, const float* __restrict__ b3, const float* __restrict__ b4,
    float* __restrict__ sgp)
{
  __shared__ u16 Xs[80*LDX + 6656];   // pad -> 55552 B -> 2 blocks/CU
  const int tid = threadIdx.x;
  const int lane = tid & 63;
  const int wv  = tid >> 6;       // 0..7 -> h-range wv*32
  const int b   = blockIdx.x;
  const int t   = blockIdx.y;
  const int l15 = lane & 15;
  const int l4  = lane >> 4;

  const float* pib = pi + b*(20*256);
  const float* pjb = pj + b*(20*256);
  const float* qab = qa + b*256;

  // ---- X1 = relu(pi + pj + qa) -> LDS bf16 ----
  #pragma unroll
  for (int it = 0; it < 5; ++it){
    int u  = it*512 + tid;
    int m  = u >> 5;
    int gq = (u & 31) << 3;
    int R  = t*80 + m;
    int i  = R / 20;
    int j  = R - i*20;
    const float4* pr = (const float4*)(pib + i*256 + gq);
    const float4* qr = (const float4*)(pjb + j*256 + gq);
    const float4* ar = (const float4*)(qab + gq);
    uint4 pk;
    {
      float4 a = pr[0], c4 = qr[0], d4 = ar[0];
      pk.x = pack2(fmaxf(a.x+c4.x+d4.x,0.f), fmaxf(a.y+c4.y+d4.y,0.f));
      pk.y = pack2(fmaxf(a.z+c4.z+d4.z,0.f), fmaxf(a.w+c4.w+d4.w,0.f));
    }
    {
      float4 a = pr[1], c4 = qr[1], d4 = ar[1];
      pk.z = pack2(fmaxf(a.x+c4.x+d4.x,0.f), fmaxf(a.y+c4.y+d4.y,0.f));
      pk.w = pack2(fmaxf(a.z+c4.z+d4.z,0.f), fmaxf(a.w+c4.w+d4.w,0.f));
    }
    *(uint4*)(&Xs[m*LDX + gq]) = pk;
  }
  __syncthreads();

  // ---- layers 1,2 (g2,g3): X <- relu(W X^T + b) in place ----
  for (int lay = 0; lay < 2; ++lay){
    const u16*   W    = lay ? w3 : w2;
    const float* bias = lay ? b3 : b2;
    f32x4 acc[2][5];
    #pragma unroll
    for (int hf=0; hf<2; hf++)
      #pragma unroll
      for (int mf=0; mf<5; mf++)
        acc[hf][mf] = (f32x4){0.f,0.f,0.f,0.f};

    #pragma unroll
    for (int kk = 0; kk < 8; ++kk){
      short8 af[2], xf[5];
      #pragma unroll
      for (int hf=0; hf<2; hf++){
        int row = wv*32 + hf*16 + l15;
        af[hf] = *(const short8*)(W + row*256 + kk*32 + l4*8);
      }
      #pragma unroll
      for (int mf=0; mf<5; mf++)
        xf[mf] = *(const short8*)(&Xs[(mf*16 + l15)*LDX + kk*32 + l4*8]);
      #pragma unroll
      for (int hf=0; hf<2; hf++)
        #pragma unroll
        for (int mf=0; mf<5; mf++)
          acc[hf][mf] = __builtin_amdgcn_mfma_f32_16x16x32_bf16(af[hf], xf[mf], acc[hf][mf], 0, 0, 0);
    }

    __syncthreads();   // all reads of Xs complete
    #pragma unroll
    for (int hf=0; hf<2; hf++){
      int h0 = wv*32 + hf*16 + l4*4;
      float4 bi = *(const float4*)(bias + h0);
      #pragma unroll
      for (int mf=0; mf<5; mf++){
        int m = mf*16 + l15;
        uint2 pk;
        pk.x = pack2(fmaxf(acc[hf][mf][0]+bi.x,0.f), fmaxf(acc[hf][mf][1]+bi.y,0.f));
        pk.y = pack2(fmaxf(acc[hf][mf][2]+bi.z,0.f), fmaxf(acc[hf][mf][3]+bi.w,0.f));
        *(uint2*)(&Xs[m*LDX + h0]) = pk;
      }
    }
    __syncthreads();
  }

  // ---- layer 3 (g4) + column-sum epilogue ----
  {
    f32x4 acc[2][5];
    #pragma unroll
    for (int hf=0; hf<2; hf++)
      #pragma unroll
      for (int mf=0; mf<5; mf++)
        acc[hf][mf] = (f32x4){0.f,0.f,0.f,0.f};

    #pragma unroll
    for (int kk = 0; kk < 8; ++kk){
      short8 af[2], xf[5];
      #pragma unroll
      for (int hf=0; hf<2; hf++){
        int row = wv*32 + hf*16 + l15;
        af[hf] = *(const short8*)(w4 + row*256 + kk*32 + l4*8);
      }
      #pragma unroll
      for (int mf=0; mf<5; mf++)
        xf[mf] = *(const short8*)(&Xs[(mf*16 + l15)*LDX + kk*32 + l4*8]);
      #pragma unroll
      for (int hf=0; hf<2; hf++)
        #pragma unroll
        for (int mf=0; mf<5; mf++)
          acc[hf][mf] = __builtin_amdgcn_mfma_f32_16x16x32_bf16(af[hf], xf[mf], acc[hf][mf], 0, 0, 0);
    }

    #pragma unroll
    for (int hf=0; hf<2; hf++){
      int h0 = wv*32 + hf*16 + l4*4;
      float4 bi = *(const float4*)(b4 + h0);
      float s0 = 0.f, s1 = 0.f, s2 = 0.f, s3 = 0.f;
      #pragma unroll
      for (int mf=0; mf<5; mf++){
        s0 += fmaxf(acc[hf][mf][0]+bi.x,0.f);
        s1 += fmaxf(acc[hf][mf][1]+bi.y,0.f);
        s2 += fmaxf(acc[hf][mf][2]+bi.z,0.f);
        s3 += fmaxf(acc[hf][mf][3]+bi.w,0.f);
      }
      float sv[4] = {s0, s1, s2, s3};
      #pragma unroll
      for (int r=0; r<4; r++){
        float v = sv[r];
        v += __shfl_xor(v, 1);
        v += __shfl_xor(v, 2);
        v += __shfl_xor(v, 4);
        v += __shfl_xor(v, 8);
        if (l15 == 0){
          int h = h0 + r;
          // [t][b][h]: block-exclusive region -> no cross-XCD false sharing
          sgp[t*131072 + b*256 + h] = v;
        }
      }
    }
  }
}

// ---------------- f1 via MFMA, 5-way partial-sum folded into B-fragment load ----------------
__global__ __launch_bounds__(256) void fcm1_kernel(
    const float* __restrict__ sgp, const u16* __restrict__ w,
    const float* __restrict__ bias, u16* __restrict__ outp)
{
  const int tid = threadIdx.x, lane = tid & 63, wv = tid >> 6;
  const int l15 = lane & 15, l4 = lane >> 4;
  const int b0 = blockIdx.x*16;
  const int of0 = blockIdx.y*4 + wv;   // 0..15
  f32x4 acc = (f32x4){0.f,0.f,0.f,0.f};
  #pragma unroll
  for (int kk=0; kk<8; ++kk){
    const float* base = sgp + (b0+l15)*256 + kk*32 + l4*8;
    float4 s0 = {0.f,0.f,0.f,0.f}, s1 = {0.f,0.f,0.f,0.f};
    #pragma unroll
    for (int t=0;t<5;t++){
      float4 a = *(const float4*)(base + t*131072);
      float4 c = *(const float4*)(base + t*131072 + 4);
      s0.x += a.x; s0.y += a.y; s0.z += a.z; s0.w += a.w;
      s1.x += c.x; s1.y += c.y; s1.z += c.z; s1.w += c.w;
    }
    union { short8 s; u32 u[4]; } xf;
    xf.u[0] = pack2(s0.x, s0.y); xf.u[1] = pack2(s0.z, s0.w);
    xf.u[2] = pack2(s1.x, s1.y); xf.u[3] = pack2(s1.z, s1.w);
    short8 af = *(const short8*)(w + (of0*16 + l15)*256 + kk*32 + l4*8);
    acc = __builtin_amdgcn_mfma_f32_16x16x32_bf16(af, xf.s, acc, 0, 0, 0);
  }
  const int b = b0 + l15;
  const int o0 = of0*16 + l4*4;
  float v0 = fmaxf(acc[0] + bias[o0+0], 0.f);
  float v1 = fmaxf(acc[1] + bias[o0+1], 0.f);
  float v2 = fmaxf(acc[2] + bias[o0+2], 0.f);
  float v3 = fmaxf(acc[3] + bias[o0+3], 0.f);
  uint2 pk;
  pk.x = pack2(v0, v1);
  pk.y = pack2(v2, v3);
  *(uint2*)(outp + (size_t)b*256 + o0) = pk;
}

// ---------------- fc layers via MFMA (output sliced over blockIdx.y) ----------------
template<int HF, int KK, int OPAD, int OREAL, int MODE>
__global__ __launch_bounds__(256) void fcm_kernel(
    const u16* __restrict__ in, const u16* __restrict__ w,
    const float* __restrict__ bias, void* __restrict__ outp)
{
  const int K = KK*32;
  const int tid = threadIdx.x, lane = tid & 63, wv = tid >> 6;
  const int l15 = lane & 15, l4 = lane >> 4;
  const int b0 = blockIdx.x*16;
  const int of0 = (blockIdx.y*4 + wv)*HF;   // output fragment base
  f32x4 acc[HF];
  #pragma unroll
  for (int hf=0; hf<HF; hf++) acc[hf] = (f32x4){0.f,0.f,0.f,0.f};
  #pragma unroll 4
  for (int kk=0; kk<KK; ++kk){
    short8 xf = *(const short8*)(in + (b0+l15)*K + kk*32 + l4*8);
    #pragma unroll
    for (int hf=0; hf<HF; hf++){
      short8 af = *(const short8*)(w + ((of0+hf)*16 + l15)*K + kk*32 + l4*8);
      acc[hf] = __builtin_amdgcn_mfma_f32_16x16x32_bf16(af, xf, acc[hf], 0, 0, 0);
    }
  }
  const int b = b0 + l15;
  #pragma unroll
  for (int hf=0; hf<HF; hf++){
    const int o0 = (of0+hf)*16 + l4*4;
    float v[4];
    #pragma unroll
    for (int r=0;r<4;r++){
      float bv = (o0+r < OREAL) ? bias[o0+r] : 0.f;
      v[r] = acc[hf][r] + bv;
    }
    if (MODE == 0){
      uint2 pk;
      pk.x = pack2(fmaxf(v[0],0.f), fmaxf(v[1],0.f));
      pk.y = pack2(fmaxf(v[2],0.f), fmaxf(v[3],0.f));
      *(uint2*)((u16*)outp + (size_t)b*OPAD + o0) = pk;
    } else {
      float* of = (float*)outp;
      #pragma unroll
      for (int r=0;r<4;r++)
        if (o0+r < OREAL) of[(size_t)b*OREAL + o0 + r] = v[r];
    }
  }
}

// ---------------- launch ----------------
extern "C" void kernel_launch(void* const* d_in, const int* in_sizes, int n_in,
                              void* d_out, int out_size, void* d_ws, size_t ws_size,
                              hipStream_t stream)
{
  const int*   story    = (const int*)d_in[0];
  const int*   question = (const int*)d_in[1];
  const float* emb   = (const float*)d_in[2];
  const float* s_wih = (const float*)d_in[3];
  const float* s_whh = (const float*)d_in[4];
  const float* s_bih = (const float*)d_in[5];
  const float* s_bhh = (const float*)d_in[6];
  const float* q_wih = (const float*)d_in[7];
  const float* q_whh = (const float*)d_in[8];
  const float* q_bih = (const float*)d_in[9];
  const float* q_bhh = (const float*)d_in[10];
  const float* g1w = (const float*)d_in[11];
  const float* g1b = (const float*)d_in[12];
  const float* g2w = (const float*)d_in[13];
  const float* g2b = (const float*)d_in[14];
  const float* g3w = (const float*)d_in[15];
  const float* g3b = (const float*)d_in[16];
  const float* g4w = (const float*)d_in[17];
  const float* g4b = (const float*)d_in[18];
  const float* f1w = (const float*)d_in[19];
  const float* f1b = (const float*)d_in[20];
  const float* f2w = (const float*)d_in[21];
  const float* f2b = (const float*)d_in[22];
  const float* f3w = (const float*)d_in[23];
  const float* f3b = (const float*)d_in[24];

  float* ws  = (float*)d_ws;
  float* xps = ws + OFF_XPS;
  float* xpq = ws + OFF_XPQ;
  float* qst = ws + OFF_QST;
  float* pi  = ws + OFF_PI;
  float* pj  = ws + OFF_PJ;
  float* qa  = ws + OFF_QA;
  float* tga = ws + OFF_TGA;
  float* tgb = ws + OFF_TGB;
  float* sgp = ws + OFF_SGP;
  u16*   wb    = (u16*)(ws + OFF_WB);
  u16*   w2b   = wb;
  u16*   w3b   = wb + 65536;
  u16*   w4b   = wb + 131072;
  u16*   stb   = (u16*)(ws + OFF_STB);
  u16*   wab   = (u16*)(ws + OFF_WAB);
  u16*   wbb   = (u16*)(ws + OFF_WBB);
  u16*   whhbs = (u16*)(ws + OFF_WHHS);
  u16*   whhbq = (u16*)(ws + OFF_WHHQ);
  u16*   wf1   = (u16*)(ws + OFF_WF1);
  u16*   wf2   = (u16*)(ws + OFF_WF2);
  u16*   wf3   = (u16*)(ws + OFF_WF3);
  u16*   act1  = (u16*)(ws + OFF_ACT1);
  u16*   act2  = (u16*)(ws + OFF_ACT2);

  prep_kernel<<<dim3(40,3), dim3(256), 0, stream>>>(
      emb, s_wih, s_bih, s_bhh, q_wih, q_bih, q_bhh,
      g2w, g3w, g4w, g1w, s_whh, q_whh, f1w, f2w, f3w,
      xps, xpq, wb, wab, wbb, tga, tgb, whhbs, whhbq, wf1, wf2, wf3);
  lstm_kernel<<<dim3(672), dim3(64), 0, stream>>>(
      story, question, xps, xpq, whhbs, whhbq, stb, qst);
  pipj_kernel<<<dim3(160,3), dim3(256), 0, stream>>>(
      stb, wab, wbb, tga, tgb, qst, g1w, g1b, pi, pj, qa);
  relnet_kernel<<<dim3(512,5), dim3(512), 0, stream>>>(
      pi, pj, qa, w2b, w3b, w4b, g2b, g3b, g4b, sgp);
  fcm1_kernel<<<dim3(32,4), dim3(256), 0, stream>>>(sgp, wf1, f1b, act1);
  fcm_kernel<2,8,512,512,0><<<dim3(32,4), dim3(256), 0, stream>>>(act1, wf2, f2b, act2);
  fcm_kernel<2,16,1024,1000,1><<<dim3(32,8), dim3(256), 0, stream>>>(act2, wf3, f3b, (float*)d_out);
}

// Round 12
// 236.023 us; speedup vs baseline: 1.3123x; 1.0346x over previous
//
#include <hip/hip_runtime.h>

typedef unsigned short u16;
typedef unsigned int   u32;
typedef __attribute__((ext_vector_type(8))) short short8;
typedef __attribute__((ext_vector_type(4))) float f32x4;

// ---------------- ws layout (float element offsets) ----------------
#define OFF_XPS   0            // 10000*128 (gate-permuted xp story)
#define OFF_XPQ   1280000      // 10000*128 (gate-permuted xp question)
#define OFF_QST   2560000      // 512*32
#define OFF_PI    2576384      // 512*20*256
#define OFF_PJ    5197824      // 512*20*256
#define OFF_QA    7819264      // 512*256
#define OFF_TGA   7950336      // 20*256
#define OFF_TGB   7955456      // 20*256
#define OFF_WB    7960576      // u16 x 196608 (g2/g3/g4 bf16)
#define OFF_STB   8058880      // u16 x 327680 (story h bf16)
#define OFF_WAB   8222720      // u16 x 8192
#define OFF_WBB   8226816      // u16 x 8192
#define OFF_WHHS  8230912      // u16 x 4096
#define OFF_WHHQ  8232960      // u16 x 4096
#define OFF_WF1   8235008      // u16 x 65536
#define OFF_WF2   8267776      // u16 x 131072
#define OFF_WF3   8333312      // u16 x 524288 (1024x512, zero-padded)
// aliased into XPS/XPQ region (dead after lstm):
#define OFF_SGP   0            // 5*256*512 fl  [t][b][h]
#define OFF_ACT1  720896       // u16 x 131072 ([b][256])
#define OFF_ACT2  786432       // u16 x 262144 ([b][512])

__device__ __forceinline__ u16 f2bf(float f){
  union { float f; u32 u; } v; v.f = f;
  u32 u = v.u;
  u32 r = u + 0x7fffu + ((u >> 16) & 1u);
  return (u16)(r >> 16);
}
__device__ __forceinline__ u32 pack2(float a, float b){
  u32 r;
  asm("v_cvt_pk_bf16_f32 %0, %1, %2" : "=v"(r) : "v"(a), "v"(b));
  return r;
}
__device__ __forceinline__ float sigm(float x){
  return __builtin_amdgcn_rcpf(1.f + __expf(-x));
}

// LDS-only release barrier: no vmcnt drain (global prefetches stay in flight).
#define LBAR() do {                                        \
    asm volatile("s_waitcnt lgkmcnt(0)" ::: "memory");     \
    __builtin_amdgcn_s_barrier();                          \
    __builtin_amdgcn_sched_barrier(0);                     \
  } while (0)

// ---------------- prep: xp tables (y=0,1) + misc conversions (y=2) ----------------
__global__ __launch_bounds__(256) void prep_kernel(
    const float* __restrict__ emb,
    const float* __restrict__ swih, const float* __restrict__ sbih, const float* __restrict__ sbhh,
    const float* __restrict__ qwih, const float* __restrict__ qbih, const float* __restrict__ qbhh,
    const float* __restrict__ g2w, const float* __restrict__ g3w, const float* __restrict__ g4w,
    const float* __restrict__ g1w,
    const float* __restrict__ swhh, const float* __restrict__ qwhh,
    const float* __restrict__ f1w, const float* __restrict__ f2w, const float* __restrict__ f3w,
    float* __restrict__ xps, float* __restrict__ xpq,
    u16* __restrict__ wb, u16* __restrict__ wab, u16* __restrict__ wbb,
    float* __restrict__ tga, float* __restrict__ tgb,
    u16* __restrict__ whhbs, u16* __restrict__ whhbq,
    u16* __restrict__ wf1, u16* __restrict__ wf2, u16* __restrict__ wf3)
{
  __shared__ float wl[4096];
  __shared__ float bl[128];
  const int tid = threadIdx.x;
  if (blockIdx.y == 2){
    const int B = 196608;
    const int C = B + 16384;
    const int D = C + 10240;
    const int E = D + 8192;
    const int F = E + 65536;
    const int G = F + 131072;
    const int H = G + 524288;
    for (int idx = blockIdx.x*256 + tid; idx < H; idx += 160*256){
      if (idx < B){
        const int k = idx;
        const float* src = (k < 65536) ? g2w : ((k < 131072) ? g3w : g4w);
        wb[k] = f2bf(src[k & 65535]);
      } else if (idx < C){
        const int k = idx - B;
        if (k < 8192) wab[k] = f2bf(g1w[(k>>5)*136 + (k&31)]);
        else { const int k2 = k - 8192; wbb[k2] = f2bf(g1w[(k2>>5)*136 + 52 + (k2&31)]); }
      } else if (idx < D){
        const int k = idx - C;
        if (k < 5120){ const int s = k >> 8, g = k & 255; tga[k] = g1w[g*136 + 32 + s]; }
        else { const int k2 = k - 5120; const int s = k2 >> 8, g = k2 & 255; tgb[k2] = g1w[g*136 + 84 + s]; }
      } else if (idx < E){
        const int k = idx - D;
        if (k < 4096) whhbs[k] = f2bf(swhh[k]);
        else whhbq[k-4096] = f2bf(qwhh[k-4096]);
      } else if (idx < F){
        const int k = idx - E;
        wf1[k] = f2bf(f1w[k]);
      } else if (idx < G){
        const int k = idx - F;
        wf2[k] = f2bf(f2w[k]);
      } else {
        const int k = idx - G;
        const int o = k >> 9, kk = k & 511;
        wf3[k] = (o < 1000) ? f2bf(f3w[o*512 + kk]) : (u16)0;
      }
    }
    return;
  }
  const bool isq = blockIdx.y;
  const float* wih = isq ? qwih : swih;
  const float* bih = isq ? qbih : sbih;
  const float* bhh = isq ? qbhh : sbhh;
  float* xp = isq ? xpq : xps;
  #pragma unroll
  for (int k=0;k<16;k++) wl[k*256+tid] = wih[k*256+tid];
  if (tid < 128) bl[tid] = bih[tid] + bhh[tid];
  __syncthreads();
  const int v = blockIdx.x*256 + tid;
  if (v >= 10000) return;
  float4 e[8];
  #pragma unroll
  for (int q=0;q<8;q++) e[q] = *(const float4*)(emb + v*32 + q*4);
  for (int g=0; g<128; ++g){
    float acc = bl[g];
    #pragma unroll
    for (int q=0;q<8;q++){
      float4 w4 = *(const float4*)(&wl[g*32 + q*4]);
      acc = fmaf(e[q].x, w4.x, acc); acc = fmaf(e[q].y, w4.y, acc);
      acc = fmaf(e[q].z, w4.z, acc); acc = fmaf(e[q].w, w4.w, acc);
    }
    xp[v*128 + (g&15)*8 + (g>>4)] = acc;
  }
}

// ---------------- LSTM via MFMA: 16 sequences per wave ----------------
template<int LEN>
__device__ __forceinline__ void lstm_mfma_run(
    const int* __restrict__ toks, int s0,
    const float* __restrict__ xpr, const u16* __restrict__ whhb,
    u16* __restrict__ hl, int lane, float* h0r, float* h1r)
{
  const int l15 = lane & 15, l4 = lane >> 4;
  short8 wf[8];
  #pragma unroll
  for (int f=0; f<8; f++)
    wf[f] = *(const short8*)(whhb + (f*16+l15)*32 + l4*8);
  short8 ha = (short8){0,0,0,0,0,0,0,0};
  float c0[4] = {0,0,0,0}, c1[4] = {0,0,0,0};
  int tk[4];
  #pragma unroll
  for (int r=0;r<4;r++) tk[r] = toks[(s0 + l4*4 + r)*LEN];
  float4 xa[4], xb[4];
  #pragma unroll
  for (int r=0;r<4;r++){
    xa[r] = *(const float4*)(xpr + tk[r]*128 + l15*8);
    xb[r] = *(const float4*)(xpr + tk[r]*128 + l15*8 + 4);
  }
  #pragma unroll
  for (int t=0; t<LEN; ++t){
    int tkn[4];
    if (t+1 < LEN){
      #pragma unroll
      for (int r=0;r<4;r++) tkn[r] = toks[(s0 + l4*4 + r)*LEN + t + 1];
    }
    const f32x4 z = (f32x4){0.f,0.f,0.f,0.f};
    f32x4 acc[8];
    #pragma unroll
    for (int f=0; f<8; f++)
      acc[f] = __builtin_amdgcn_mfma_f32_16x16x32_bf16(ha, wf[f], z, 0, 0, 0);
    float4 na[4], nb[4];
    if (t+1 < LEN){
      #pragma unroll
      for (int r=0;r<4;r++){
        na[r] = *(const float4*)(xpr + tkn[r]*128 + l15*8);
        nb[r] = *(const float4*)(xpr + tkn[r]*128 + l15*8 + 4);
      }
    }
    #pragma unroll
    for (int r=0;r<4;r++){
      float i0 = sigm(acc[0][r] + xa[r].x);
      float f0 = sigm(acc[2][r] + xa[r].z);
      float g0 = 2.f*sigm(2.f*(acc[4][r] + xb[r].x)) - 1.f;
      float o0 = sigm(acc[6][r] + xb[r].z);
      c0[r] = fmaf(f0, c0[r], i0*g0);
      h0r[r] = o0 * (2.f*sigm(2.f*c0[r]) - 1.f);
      float i1 = sigm(acc[1][r] + xa[r].y);
      float f1v = sigm(acc[3][r] + xa[r].w);
      float g1v = 2.f*sigm(2.f*(acc[5][r] + xb[r].y)) - 1.f;
      float o1 = sigm(acc[7][r] + xb[r].w);
      c1[r] = fmaf(f1v, c1[r], i1*g1v);
      h1r[r] = o1 * (2.f*sigm(2.f*c1[r]) - 1.f);
    }
    if (t+1 < LEN){
      #pragma unroll
      for (int r=0;r<4;r++){
        hl[(l4*4+r)*32 + l15]      = f2bf(h0r[r]);
        hl[(l4*4+r)*32 + 16 + l15] = f2bf(h1r[r]);
      }
      __syncthreads();
      ha = *(const short8*)(hl + l15*32 + l4*8);
      #pragma unroll
      for (int r=0;r<4;r++){ xa[r] = na[r]; xb[r] = nb[r]; }
    }
  }
}

__global__ __launch_bounds__(64) void lstm_kernel(
    const int* __restrict__ story, const int* __restrict__ question,
    const float* __restrict__ xprs, const float* __restrict__ xprq,
    const u16* __restrict__ whhbs, const u16* __restrict__ whhbq,
    u16* __restrict__ stb, float* __restrict__ qst)
{
  __shared__ u16 hl[512];
  const int lane = threadIdx.x;
  const int w = blockIdx.x;
  const int l15 = lane & 15, l4 = lane >> 4;
  float h0r[4], h1r[4];
  if (w >= 640){
    const int s0 = (w - 640)*16;
    lstm_mfma_run<16>(question, s0, xprq, whhbq, hl, lane, h0r, h1r);
    #pragma unroll
    for (int r=0;r<4;r++){
      qst[(s0 + l4*4 + r)*32 + l15]      = h0r[r];
      qst[(s0 + l4*4 + r)*32 + 16 + l15] = h1r[r];
    }
  } else {
    const int s0 = w*16;
    lstm_mfma_run<32>(story, s0, xprs, whhbs, hl, lane, h0r, h1r);
    #pragma unroll
    for (int r=0;r<4;r++){
      stb[(s0 + l4*4 + r)*32 + l15]      = f2bf(h0r[r]);
      stb[(s0 + l4*4 + r)*32 + 16 + l15] = f2bf(h1r[r]);
    }
  }
}

// ---------------- pi / pj via MFMA (K=32, one step); y==2 computes qa ----------------
__global__ __launch_bounds__(256) void pipj_kernel(
    const u16* __restrict__ stb, const u16* __restrict__ wab, const u16* __restrict__ wbb,
    const float* __restrict__ tga, const float* __restrict__ tgb,
    const float* __restrict__ qst, const float* __restrict__ g1w, const float* __restrict__ g1b,
    float* __restrict__ pi, float* __restrict__ pj, float* __restrict__ qa)
{
  const int tid = threadIdx.x;
  if (blockIdx.y == 2){
    for (int idx = blockIdx.x*256 + tid; idx < 131072; idx += 160*256){
      const int b = idx >> 8, g = idx & 255;
      const float* qs = qst + b*32;
      const float* wr = g1w + g*136 + 104;
      float acc = g1b[g];
      #pragma unroll
      for (int q=0;q<8;q++){
        float4 s4 = *(const float4*)(qs + q*4);
        float4 w4 = *(const float4*)(wr + q*4);
        acc = fmaf(s4.x, w4.x, acc); acc = fmaf(s4.y, w4.y, acc);
        acc = fmaf(s4.z, w4.z, acc); acc = fmaf(s4.w, w4.w, acc);
      }
      qa[idx] = acc;
    }
    return;
  }
  const int lane = tid & 63;
  const int wv = tid >> 6;
  const int l15 = lane & 15;
  const int l4r = lane >> 4;
  const int bs0 = blockIdx.x * 64;
  const bool isj = blockIdx.y;
  const u16* wB = isj ? wbb : wab;
  const float* tg = isj ? tgb : tga;
  float* out = isj ? pj : pi;

  short8 af[4], bf[4];
  #pragma unroll
  for (int mf=0; mf<4; mf++)
    af[mf] = *(const short8*)(stb + (bs0 + mf*16 + l15)*32 + l4r*8);
  #pragma unroll
  for (int nf=0; nf<4; nf++)
    bf[nf] = *(const short8*)(wB + (wv*64 + nf*16 + l15)*32 + l4r*8);

  #pragma unroll
  for (int mf=0; mf<4; mf++){
    #pragma unroll
    for (int nf=0; nf<4; nf++){
      f32x4 acc = (f32x4){0.f,0.f,0.f,0.f};
      acc = __builtin_amdgcn_mfma_f32_16x16x32_bf16(af[mf], bf[nf], acc, 0, 0, 0);
      const int g = wv*64 + nf*16 + l15;
      #pragma unroll
      for (int r=0; r<4; r++){
        const int bs = bs0 + mf*16 + l4r*4 + r;
        const int s = bs % 20;
        out[bs*256 + g] = acc[r] + tg[s*256 + g];
      }
    }
  }
}

// ---------------- core relational MLP: 8-wave blocks, raw barriers + af prefetch ----------------
// grid (512 b, 5 t) x 512 threads; X tile bf16 in LDS [80][264].
// LDS padded to 55.5KB -> 2 blocks/CU -> 4 waves/SIMD -> VGPR cap 128.
// Barriers are LDS-release only (no vmcnt drain): af global loads double-buffered
// across kk AND across layer boundaries, staying in flight through writeback.
#define LDX 264
__global__ __launch_bounds__(512) void relnet_kernel(
    const float* __restrict__ pi, const float* __restrict__ pj, const float* __restrict__ qa,
    const u16* __restrict__ w2, const u16* __restrict__ w3, const u16* __restrict__ w4,
    const float* __restrict__ b2, const float* __restrict__ b3, const float* __restrict__ b4,
    float* __restrict__ sgp)
{
  __shared__ u16 Xs[80*LDX + 6656];   // pad -> 55552 B -> 2 blocks/CU
  const int tid = threadIdx.x;
  const int lane = tid & 63;
  const int wv  = tid >> 6;       // 0..7 -> h-range wv*32
  const int b   = blockIdx.x;
  const int t   = blockIdx.y;
  const int l15 = lane & 15;
  const int l4  = lane >> 4;

  const float* pib = pi + b*(20*256);
  const float* pjb = pj + b*(20*256);
  const float* qab = qa + b*256;

  const int ar0 = (wv*32 + l15)*256 + l4*8;        // af row offsets (hf=0/1)
  const int ar1 = (wv*32 + 16 + l15)*256 + l4*8;

  // ---- X1 = relu(pi + pj + qa) -> LDS bf16 ----
  #pragma unroll
  for (int it = 0; it < 5; ++it){
    int u  = it*512 + tid;
    int m  = u >> 5;
    int gq = (u & 31) << 3;
    int R  = t*80 + m;
    int i  = R / 20;
    int j  = R - i*20;
    const float4* pr = (const float4*)(pib + i*256 + gq);
    const float4* qr = (const float4*)(pjb + j*256 + gq);
    const float4* ar = (const float4*)(qab + gq);
    uint4 pk;
    {
      float4 a = pr[0], c4 = qr[0], d4 = ar[0];
      pk.x = pack2(fmaxf(a.x+c4.x+d4.x,0.f), fmaxf(a.y+c4.y+d4.y,0.f));
      pk.y = pack2(fmaxf(a.z+c4.z+d4.z,0.f), fmaxf(a.w+c4.w+d4.w,0.f));
    }
    {
      float4 a = pr[1], c4 = qr[1], d4 = ar[1];
      pk.z = pack2(fmaxf(a.x+c4.x+d4.x,0.f), fmaxf(a.y+c4.y+d4.y,0.f));
      pk.w = pack2(fmaxf(a.z+c4.z+d4.z,0.f), fmaxf(a.w+c4.w+d4.w,0.f));
    }
    *(uint4*)(&Xs[m*LDX + gq]) = pk;
  }

  // prefetch layer-0 kk=0 A-fragments (stays in flight across the barrier)
  short8 pf0 = *(const short8*)(w2 + ar0);
  short8 pf1 = *(const short8*)(w2 + ar1);

  LBAR();   // stage writes visible; no vmcnt drain

  // ---- layers 1,2 (g2,g3): X <- relu(W X^T + b) in place ----
  #pragma unroll
  for (int lay = 0; lay < 2; ++lay){
    const u16*   W    = lay ? w3 : w2;
    const u16*   Wn   = lay ? w4 : w3;
    const float* bias = lay ? b3 : b2;
    f32x4 acc[2][5];
    #pragma unroll
    for (int hf=0; hf<2; hf++)
      #pragma unroll
      for (int mf=0; mf<5; mf++)
        acc[hf][mf] = (f32x4){0.f,0.f,0.f,0.f};

    #pragma unroll
    for (int kk = 0; kk < 8; ++kk){
      short8 a0 = pf0, a1 = pf1;
      const u16* src = (kk < 7) ? W : Wn;
      const int  kn  = (kk < 7) ? (kk+1)*32 : 0;
      pf0 = *(const short8*)(src + ar0 + kn);
      pf1 = *(const short8*)(src + ar1 + kn);
      short8 xf[5];
      #pragma unroll
      for (int mf=0; mf<5; mf++)
        xf[mf] = *(const short8*)(&Xs[(mf*16 + l15)*LDX + kk*32 + l4*8]);
      #pragma unroll
      for (int mf=0; mf<5; mf++){
        acc[0][mf] = __builtin_amdgcn_mfma_f32_16x16x32_bf16(a0, xf[mf], acc[0][mf], 0, 0, 0);
        acc[1][mf] = __builtin_amdgcn_mfma_f32_16x16x32_bf16(a1, xf[mf], acc[1][mf], 0, 0, 0);
      }
    }

    LBAR();   // all reads of Xs complete (LDS only; pf0/pf1 remain in flight)
    #pragma unroll
    for (int hf=0; hf<2; hf++){
      int h0 = wv*32 + hf*16 + l4*4;
      float4 bi = *(const float4*)(bias + h0);
      #pragma unroll
      for (int mf=0; mf<5; mf++){
        int m = mf*16 + l15;
        uint2 pk;
        pk.x = pack2(fmaxf(acc[hf][mf][0]+bi.x,0.f), fmaxf(acc[hf][mf][1]+bi.y,0.f));
        pk.y = pack2(fmaxf(acc[hf][mf][2]+bi.z,0.f), fmaxf(acc[hf][mf][3]+bi.w,0.f));
        *(uint2*)(&Xs[m*LDX + h0]) = pk;
      }
    }
    LBAR();   // writes visible
  }

  // ---- layer 3 (g4) + column-sum epilogue (pf holds w4 kk=0) ----
  {
    f32x4 acc[2][5];
    #pragma unroll
    for (int hf=0; hf<2; hf++)
      #pragma unroll
      for (int mf=0; mf<5; mf++)
        acc[hf][mf] = (f32x4){0.f,0.f,0.f,0.f};

    #pragma unroll
    for (int kk = 0; kk < 8; ++kk){
      short8 a0 = pf0, a1 = pf1;
      if (kk < 7){
        pf0 = *(const short8*)(w4 + ar0 + (kk+1)*32);
        pf1 = *(const short8*)(w4 + ar1 + (kk+1)*32);
      }
      short8 xf[5];
      #pragma unroll
      for (int mf=0; mf<5; mf++)
        xf[mf] = *(const short8*)(&Xs[(mf*16 + l15)*LDX + kk*32 + l4*8]);
      #pragma unroll
      for (int mf=0; mf<5; mf++){
        acc[0][mf] = __builtin_amdgcn_mfma_f32_16x16x32_bf16(a0, xf[mf], acc[0][mf], 0, 0, 0);
        acc[1][mf] = __builtin_amdgcn_mfma_f32_16x16x32_bf16(a1, xf[mf], acc[1][mf], 0, 0, 0);
      }
    }

    #pragma unroll
    for (int hf=0; hf<2; hf++){
      int h0 = wv*32 + hf*16 + l4*4;
      float4 bi = *(const float4*)(b4 + h0);
      float s0 = 0.f, s1 = 0.f, s2 = 0.f, s3 = 0.f;
      #pragma unroll
      for (int mf=0; mf<5; mf++){
        s0 += fmaxf(acc[hf][mf][0]+bi.x,0.f);
        s1 += fmaxf(acc[hf][mf][1]+bi.y,0.f);
        s2 += fmaxf(acc[hf][mf][2]+bi.z,0.f);
        s3 += fmaxf(acc[hf][mf][3]+bi.w,0.f);
      }
      float sv[4] = {s0, s1, s2, s3};
      #pragma unroll
      for (int r=0; r<4; r++){
        float v = sv[r];
        v += __shfl_xor(v, 1);
        v += __shfl_xor(v, 2);
        v += __shfl_xor(v, 4);
        v += __shfl_xor(v, 8);
        if (l15 == 0){
          int h = h0 + r;
          // [t][b][h]: block-exclusive region -> no cross-XCD false sharing
          sgp[t*131072 + b*256 + h] = v;
        }
      }
    }
  }
}

// ---------------- f1 via MFMA, 5-way partial-sum folded into B-fragment load ----------------
__global__ __launch_bounds__(256) void fcm1_kernel(
    const float* __restrict__ sgp, const u16* __restrict__ w,
    const float* __restrict__ bias, u16* __restrict__ outp)
{
  const int tid = threadIdx.x, lane = tid & 63, wv = tid >> 6;
  const int l15 = lane & 15, l4 = lane >> 4;
  const int b0 = blockIdx.x*16;
  const int of0 = blockIdx.y*4 + wv;   // 0..15
  f32x4 acc = (f32x4){0.f,0.f,0.f,0.f};
  #pragma unroll
  for (int kk=0; kk<8; ++kk){
    const float* base = sgp + (b0+l15)*256 + kk*32 + l4*8;
    float4 s0 = {0.f,0.f,0.f,0.f}, s1 = {0.f,0.f,0.f,0.f};
    #pragma unroll
    for (int t=0;t<5;t++){
      float4 a = *(const float4*)(base + t*131072);
      float4 c = *(const float4*)(base + t*131072 + 4);
      s0.x += a.x; s0.y += a.y; s0.z += a.z; s0.w += a.w;
      s1.x += c.x; s1.y += c.y; s1.z += c.z; s1.w += c.w;
    }
    union { short8 s; u32 u[4]; } xf;
    xf.u[0] = pack2(s0.x, s0.y); xf.u[1] = pack2(s0.z, s0.w);
    xf.u[2] = pack2(s1.x, s1.y); xf.u[3] = pack2(s1.z, s1.w);
    short8 af = *(const short8*)(w + (of0*16 + l15)*256 + kk*32 + l4*8);
    acc = __builtin_amdgcn_mfma_f32_16x16x32_bf16(af, xf.s, acc, 0, 0, 0);
  }
  const int b = b0 + l15;
  const int o0 = of0*16 + l4*4;
  float v0 = fmaxf(acc[0] + bias[o0+0], 0.f);
  float v1 = fmaxf(acc[1] + bias[o0+1], 0.f);
  float v2 = fmaxf(acc[2] + bias[o0+2], 0.f);
  float v3 = fmaxf(acc[3] + bias[o0+3], 0.f);
  uint2 pk;
  pk.x = pack2(v0, v1);
  pk.y = pack2(v2, v3);
  *(uint2*)(outp + (size_t)b*256 + o0) = pk;
}

// ---------------- fc layers via MFMA (output sliced over blockIdx.y) ----------------
template<int HF, int KK, int OPAD, int OREAL, int MODE>
__global__ __launch_bounds__(256) void fcm_kernel(
    const u16* __restrict__ in, const u16* __restrict__ w,
    const float* __restrict__ bias, void* __restrict__ outp)
{
  const int K = KK*32;
  const int tid = threadIdx.x, lane = tid & 63, wv = tid >> 6;
  const int l15 = lane & 15, l4 = lane >> 4;
  const int b0 = blockIdx.x*16;
  const int of0 = (blockIdx.y*4 + wv)*HF;   // output fragment base
  f32x4 acc[HF];
  #pragma unroll
  for (int hf=0; hf<HF; hf++) acc[hf] = (f32x4){0.f,0.f,0.f,0.f};
  #pragma unroll 4
  for (int kk=0; kk<KK; ++kk){
    short8 xf = *(const short8*)(in + (b0+l15)*K + kk*32 + l4*8);
    #pragma unroll
    for (int hf=0; hf<HF; hf++){
      short8 af = *(const short8*)(w + ((of0+hf)*16 + l15)*K + kk*32 + l4*8);
      acc[hf] = __builtin_amdgcn_mfma_f32_16x16x32_bf16(af, xf, acc[hf], 0, 0, 0);
    }
  }
  const int b = b0 + l15;
  #pragma unroll
  for (int hf=0; hf<HF; hf++){
    const int o0 = (of0+hf)*16 + l4*4;
    float v[4];
    #pragma unroll
    for (int r=0;r<4;r++){
      float bv = (o0+r < OREAL) ? bias[o0+r] : 0.f;
      v[r] = acc[hf][r] + bv;
    }
    if (MODE == 0){
      uint2 pk;
      pk.x = pack2(fmaxf(v[0],0.f), fmaxf(v[1],0.f));
      pk.y = pack2(fmaxf(v[2],0.f), fmaxf(v[3],0.f));
      *(uint2*)((u16*)outp + (size_t)b*OPAD + o0) = pk;
    } else {
      float* of = (float*)outp;
      #pragma unroll
      for (int r=0;r<4;r++)
        if (o0+r < OREAL) of[(size_t)b*OREAL + o0 + r] = v[r];
    }
  }
}

// ---------------- launch ----------------
extern "C" void kernel_launch(void* const* d_in, const int* in_sizes, int n_in,
                              void* d_out, int out_size, void* d_ws, size_t ws_size,
                              hipStream_t stream)
{
  const int*   story    = (const int*)d_in[0];
  const int*   question = (const int*)d_in[1];
  const float* emb   = (const float*)d_in[2];
  const float* s_wih = (const float*)d_in[3];
  const float* s_whh = (const float*)d_in[4];
  const float* s_bih = (const float*)d_in[5];
  const float* s_bhh = (const float*)d_in[6];
  const float* q_wih = (const float*)d_in[7];
  const float* q_whh = (const float*)d_in[8];
  const float* q_bih = (const float*)d_in[9];
  const float* q_bhh = (const float*)d_in[10];
  const float* g1w = (const float*)d_in[11];
  const float* g1b = (const float*)d_in[12];
  const float* g2w = (const float*)d_in[13];
  const float* g2b = (const float*)d_in[14];
  const float* g3w = (const float*)d_in[15];
  const float* g3b = (const float*)d_in[16];
  const float* g4w = (const float*)d_in[17];
  const float* g4b = (const float*)d_in[18];
  const float* f1w = (const float*)d_in[19];
  const float* f1b = (const float*)d_in[20];
  const float* f2w = (const float*)d_in[21];
  const float* f2b = (const float*)d_in[22];
  const float* f3w = (const float*)d_in[23];
  const float* f3b = (const float*)d_in[24];

  float* ws  = (float*)d_ws;
  float* xps = ws + OFF_XPS;
  float* xpq = ws + OFF_XPQ;
  float* qst = ws + OFF_QST;
  float* pi  = ws + OFF_PI;
  float* pj  = ws + OFF_PJ;
  float* qa  = ws + OFF_QA;
  float* tga = ws + OFF_TGA;
  float* tgb = ws + OFF_TGB;
  float* sgp = ws + OFF_SGP;
  u16*   wb    = (u16*)(ws + OFF_WB);
  u16*   w2b   = wb;
  u16*   w3b   = wb + 65536;
  u16*   w4b   = wb + 131072;
  u16*   stb   = (u16*)(ws + OFF_STB);
  u16*   wab   = (u16*)(ws + OFF_WAB);
  u16*   wbb   = (u16*)(ws + OFF_WBB);
  u16*   whhbs = (u16*)(ws + OFF_WHHS);
  u16*   whhbq = (u16*)(ws + OFF_WHHQ);
  u16*   wf1   = (u16*)(ws + OFF_WF1);
  u16*   wf2   = (u16*)(ws + OFF_WF2);
  u16*   wf3   = (u16*)(ws + OFF_WF3);
  u16*   act1  = (u16*)(ws + OFF_ACT1);
  u16*   act2  = (u16*)(ws + OFF_ACT2);

  prep_kernel<<<dim3(160,3), dim3(256), 0, stream>>>(
      emb, s_wih, s_bih, s_bhh, q_wih, q_bih, q_bhh,
      g2w, g3w, g4w, g1w, s_whh, q_whh, f1w, f2w, f3w,
      xps, xpq, wb, wab, wbb, tga, tgb, whhbs, whhbq, wf1, wf2, wf3);
  lstm_kernel<<<dim3(672), dim3(64), 0, stream>>>(
      story, question, xps, xpq, whhbs, whhbq, stb, qst);
  pipj_kernel<<<dim3(160,3), dim3(256), 0, stream>>>(
      stb, wab, wbb, tga, tgb, qst, g1w, g1b, pi, pj, qa);
  relnet_kernel<<<dim3(512,5), dim3(512), 0, stream>>>(
      pi, pj, qa, w2b, w3b, w4b, g2b, g3b, g4b, sgp);
  fcm1_kernel<<<dim3(32,4), dim3(256), 0, stream>>>(sgp, wf1, f1b, act1);
  fcm_kernel<2,8,512,512,0><<<dim3(32,4), dim3(256), 0, stream>>>(act1, wf2, f2b, act2);
  fcm_kernel<2,16,1024,1000,1><<<dim3(32,8), dim3(256), 0, stream>>>(act2, wf3, f3b, (float*)d_out);
}

// Round 13
// 231.627 us; speedup vs baseline: 1.3372x; 1.0190x over previous
//
#include <hip/hip_runtime.h>

typedef unsigned short u16;
typedef unsigned int   u32;
typedef __attribute__((ext_vector_type(8))) short short8;
typedef __attribute__((ext_vector_type(4))) float f32x4;

// ---------------- ws layout (float element offsets) ----------------
#define OFF_XPS   0            // 10000*128 (gate-permuted xp story)
#define OFF_XPQ   1280000      // 10000*128 (gate-permuted xp question)
#define OFF_QST   2560000      // 512*32
#define OFF_PI    2576384      // 512*20*256
#define OFF_PJ    5197824      // 512*20*256
#define OFF_QA    7819264      // 512*256
#define OFF_TGA   7950336      // 20*256
#define OFF_TGB   7955456      // 20*256
#define OFF_WB    7960576      // u16 x 196608 (g2/g3/g4 bf16)
#define OFF_STB   8058880      // u16 x 327680 (story h bf16)
#define OFF_WAB   8222720      // u16 x 8192
#define OFF_WBB   8226816      // u16 x 8192
#define OFF_WHHS  8230912      // u16 x 4096
#define OFF_WHHQ  8232960      // u16 x 4096
#define OFF_WF1   8235008      // u16 x 65536
#define OFF_WF2   8267776      // u16 x 131072
#define OFF_WF3   8333312      // u16 x 524288 (1024x512, zero-padded)
// aliased into XPS/XPQ region (dead after lstm):
#define OFF_SGP   0            // 5*256*512 fl  [t][b][h]
#define OFF_ACT1  720896       // u16 x 131072 ([b][256])
#define OFF_ACT2  786432       // u16 x 262144 ([b][512])

__device__ __forceinline__ u16 f2bf(float f){
  union { float f; u32 u; } v; v.f = f;
  u32 u = v.u;
  u32 r = u + 0x7fffu + ((u >> 16) & 1u);
  return (u16)(r >> 16);
}
__device__ __forceinline__ u32 pack2(float a, float b){
  u32 r;
  asm("v_cvt_pk_bf16_f32 %0, %1, %2" : "=v"(r) : "v"(a), "v"(b));
  return r;
}
__device__ __forceinline__ float sigm(float x){
  return __builtin_amdgcn_rcpf(1.f + __expf(-x));
}

// LDS-only release barrier: no vmcnt drain (global prefetches stay in flight).
#define LBAR() do {                                        \
    asm volatile("s_waitcnt lgkmcnt(0)" ::: "memory");     \
    __builtin_amdgcn_s_barrier();                          \
    __builtin_amdgcn_sched_barrier(0);                     \
  } while (0)

// ---------------- prep: xp tables (y=0,1; g-split over x) + misc (y=2) ----------------
__global__ __launch_bounds__(256) void prep_kernel(
    const float* __restrict__ emb,
    const float* __restrict__ swih, const float* __restrict__ sbih, const float* __restrict__ sbhh,
    const float* __restrict__ qwih, const float* __restrict__ qbih, const float* __restrict__ qbhh,
    const float* __restrict__ g2w, const float* __restrict__ g3w, const float* __restrict__ g4w,
    const float* __restrict__ g1w,
    const float* __restrict__ swhh, const float* __restrict__ qwhh,
    const float* __restrict__ f1w, const float* __restrict__ f2w, const float* __restrict__ f3w,
    float* __restrict__ xps, float* __restrict__ xpq,
    u16* __restrict__ wb, u16* __restrict__ wab, u16* __restrict__ wbb,
    float* __restrict__ tga, float* __restrict__ tgb,
    u16* __restrict__ whhbs, u16* __restrict__ whhbq,
    u16* __restrict__ wf1, u16* __restrict__ wf2, u16* __restrict__ wf3)
{
  __shared__ float wl[2048];
  __shared__ float bl[64];
  const int tid = threadIdx.x;
  if (blockIdx.y == 2){
    const int B = 196608;
    const int C = B + 16384;
    const int D = C + 10240;
    const int E = D + 8192;
    const int F = E + 65536;
    const int G = F + 131072;
    const int H = G + 524288;
    for (int idx = blockIdx.x*256 + tid; idx < H; idx += 160*256){
      if (idx < B){
        const int k = idx;
        const float* src = (k < 65536) ? g2w : ((k < 131072) ? g3w : g4w);
        wb[k] = f2bf(src[k & 65535]);
      } else if (idx < C){
        const int k = idx - B;
        if (k < 8192) wab[k] = f2bf(g1w[(k>>5)*136 + (k&31)]);
        else { const int k2 = k - 8192; wbb[k2] = f2bf(g1w[(k2>>5)*136 + 52 + (k2&31)]); }
      } else if (idx < D){
        const int k = idx - C;
        if (k < 5120){ const int s = k >> 8, g = k & 255; tga[k] = g1w[g*136 + 32 + s]; }
        else { const int k2 = k - 5120; const int s = k2 >> 8, g = k2 & 255; tgb[k2] = g1w[g*136 + 84 + s]; }
      } else if (idx < E){
        const int k = idx - D;
        if (k < 4096) whhbs[k] = f2bf(swhh[k]);
        else whhbq[k-4096] = f2bf(qwhh[k-4096]);
      } else if (idx < F){
        const int k = idx - E;
        wf1[k] = f2bf(f1w[k]);
      } else if (idx < G){
        const int k = idx - F;
        wf2[k] = f2bf(f2w[k]);
      } else {
        const int k = idx - G;
        const int o = k >> 9, kk = k & 511;
        wf3[k] = (o < 1000) ? f2bf(f3w[o*512 + kk]) : (u16)0;
      }
    }
    return;
  }
  if (blockIdx.x >= 80) return;
  const bool isq = blockIdx.y;
  const float* wih = isq ? qwih : swih;
  const float* bih = isq ? qbih : sbih;
  const float* bhh = isq ? qbhh : sbhh;
  float* xp = isq ? xpq : xps;
  const int gh = (blockIdx.x & 1) * 64;   // g-half this block computes
  #pragma unroll
  for (int k=0;k<8;k++) wl[k*256+tid] = wih[gh*32 + k*256 + tid];
  if (tid < 64) bl[tid] = bih[gh+tid] + bhh[gh+tid];
  __syncthreads();
  const int v = (blockIdx.x >> 1)*256 + tid;
  if (v >= 10000) return;
  float4 e[8];
  #pragma unroll
  for (int q=0;q<8;q++) e[q] = *(const float4*)(emb + v*32 + q*4);
  for (int g2=0; g2<64; ++g2){
    const int g = gh + g2;
    float acc = bl[g2];
    #pragma unroll
    for (int q=0;q<8;q++){
      float4 w4 = *(const float4*)(&wl[g2*32 + q*4]);
      acc = fmaf(e[q].x, w4.x, acc); acc = fmaf(e[q].y, w4.y, acc);
      acc = fmaf(e[q].z, w4.z, acc); acc = fmaf(e[q].w, w4.w, acc);
    }
    xp[v*128 + (g&15)*8 + (g>>4)] = acc;
  }
}

// ---------------- LSTM via MFMA: 16 sequences per wave ----------------
template<int LEN>
__device__ __forceinline__ void lstm_mfma_run(
    const int* __restrict__ toks, int s0,
    const float* __restrict__ xpr, const u16* __restrict__ whhb,
    u16* __restrict__ hl, int lane, float* h0r, float* h1r)
{
  const int l15 = lane & 15, l4 = lane >> 4;
  short8 wf[8];
  #pragma unroll
  for (int f=0; f<8; f++)
    wf[f] = *(const short8*)(whhb + (f*16+l15)*32 + l4*8);
  short8 ha = (short8){0,0,0,0,0,0,0,0};
  float c0[4] = {0,0,0,0}, c1[4] = {0,0,0,0};
  int tk[4];
  #pragma unroll
  for (int r=0;r<4;r++) tk[r] = toks[(s0 + l4*4 + r)*LEN];
  float4 xa[4], xb[4];
  #pragma unroll
  for (int r=0;r<4;r++){
    xa[r] = *(const float4*)(xpr + tk[r]*128 + l15*8);
    xb[r] = *(const float4*)(xpr + tk[r]*128 + l15*8 + 4);
  }
  #pragma unroll
  for (int t=0; t<LEN; ++t){
    int tkn[4];
    if (t+1 < LEN){
      #pragma unroll
      for (int r=0;r<4;r++) tkn[r] = toks[(s0 + l4*4 + r)*LEN + t + 1];
    }
    const f32x4 z = (f32x4){0.f,0.f,0.f,0.f};
    f32x4 acc[8];
    #pragma unroll
    for (int f=0; f<8; f++)
      acc[f] = __builtin_amdgcn_mfma_f32_16x16x32_bf16(ha, wf[f], z, 0, 0, 0);
    float4 na[4], nb[4];
    if (t+1 < LEN){
      #pragma unroll
      for (int r=0;r<4;r++){
        na[r] = *(const float4*)(xpr + tkn[r]*128 + l15*8);
        nb[r] = *(const float4*)(xpr + tkn[r]*128 + l15*8 + 4);
      }
    }
    #pragma unroll
    for (int r=0;r<4;r++){
      float i0 = sigm(acc[0][r] + xa[r].x);
      float f0 = sigm(acc[2][r] + xa[r].z);
      float g0 = 2.f*sigm(2.f*(acc[4][r] + xb[r].x)) - 1.f;
      float o0 = sigm(acc[6][r] + xb[r].z);
      c0[r] = fmaf(f0, c0[r], i0*g0);
      h0r[r] = o0 * (2.f*sigm(2.f*c0[r]) - 1.f);
      float i1 = sigm(acc[1][r] + xa[r].y);
      float f1v = sigm(acc[3][r] + xa[r].w);
      float g1v = 2.f*sigm(2.f*(acc[5][r] + xb[r].y)) - 1.f;
      float o1 = sigm(acc[7][r] + xb[r].w);
      c1[r] = fmaf(f1v, c1[r], i1*g1v);
      h1r[r] = o1 * (2.f*sigm(2.f*c1[r]) - 1.f);
    }
    if (t+1 < LEN){
      #pragma unroll
      for (int r=0;r<4;r++){
        hl[(l4*4+r)*32 + l15]      = f2bf(h0r[r]);
        hl[(l4*4+r)*32 + 16 + l15] = f2bf(h1r[r]);
      }
      __syncthreads();
      ha = *(const short8*)(hl + l15*32 + l4*8);
      #pragma unroll
      for (int r=0;r<4;r++){ xa[r] = na[r]; xb[r] = nb[r]; }
    }
  }
}

__global__ __launch_bounds__(64) void lstm_kernel(
    const int* __restrict__ story, const int* __restrict__ question,
    const float* __restrict__ xprs, const float* __restrict__ xprq,
    const u16* __restrict__ whhbs, const u16* __restrict__ whhbq,
    u16* __restrict__ stb, float* __restrict__ qst)
{
  __shared__ u16 hl[512];
  const int lane = threadIdx.x;
  const int w = blockIdx.x;
  const int l15 = lane & 15, l4 = lane >> 4;
  float h0r[4], h1r[4];
  if (w >= 640){
    const int s0 = (w - 640)*16;
    lstm_mfma_run<16>(question, s0, xprq, whhbq, hl, lane, h0r, h1r);
    #pragma unroll
    for (int r=0;r<4;r++){
      qst[(s0 + l4*4 + r)*32 + l15]      = h0r[r];
      qst[(s0 + l4*4 + r)*32 + 16 + l15] = h1r[r];
    }
  } else {
    const int s0 = w*16;
    lstm_mfma_run<32>(story, s0, xprs, whhbs, hl, lane, h0r, h1r);
    #pragma unroll
    for (int r=0;r<4;r++){
      stb[(s0 + l4*4 + r)*32 + l15]      = f2bf(h0r[r]);
      stb[(s0 + l4*4 + r)*32 + 16 + l15] = f2bf(h1r[r]);
    }
  }
}

// ---------------- pi / pj via MFMA (K=32, one step); y==2 computes qa ----------------
__global__ __launch_bounds__(256) void pipj_kernel(
    const u16* __restrict__ stb, const u16* __restrict__ wab, const u16* __restrict__ wbb,
    const float* __restrict__ tga, const float* __restrict__ tgb,
    const float* __restrict__ qst, const float* __restrict__ g1w, const float* __restrict__ g1b,
    float* __restrict__ pi, float* __restrict__ pj, float* __restrict__ qa)
{
  const int tid = threadIdx.x;
  if (blockIdx.y == 2){
    for (int idx = blockIdx.x*256 + tid; idx < 131072; idx += 160*256){
      const int b = idx >> 8, g = idx & 255;
      const float* qs = qst + b*32;
      const float* wr = g1w + g*136 + 104;
      float acc = g1b[g];
      #pragma unroll
      for (int q=0;q<8;q++){
        float4 s4 = *(const float4*)(qs + q*4);
        float4 w4 = *(const float4*)(wr + q*4);
        acc = fmaf(s4.x, w4.x, acc); acc = fmaf(s4.y, w4.y, acc);
        acc = fmaf(s4.z, w4.z, acc); acc = fmaf(s4.w, w4.w, acc);
      }
      qa[idx] = acc;
    }
    return;
  }
  const int lane = tid & 63;
  const int wv = tid >> 6;
  const int l15 = lane & 15;
  const int l4r = lane >> 4;
  const int bs0 = blockIdx.x * 64;
  const bool isj = blockIdx.y;
  const u16* wB = isj ? wbb : wab;
  const float* tg = isj ? tgb : tga;
  float* out = isj ? pj : pi;

  short8 af[4], bf[4];
  #pragma unroll
  for (int mf=0; mf<4; mf++)
    af[mf] = *(const short8*)(stb + (bs0 + mf*16 + l15)*32 + l4r*8);
  #pragma unroll
  for (int nf=0; nf<4; nf++)
    bf[nf] = *(const short8*)(wB + (wv*64 + nf*16 + l15)*32 + l4r*8);

  #pragma unroll
  for (int mf=0; mf<4; mf++){
    #pragma unroll
    for (int nf=0; nf<4; nf++){
      f32x4 acc = (f32x4){0.f,0.f,0.f,0.f};
      acc = __builtin_amdgcn_mfma_f32_16x16x32_bf16(af[mf], bf[nf], acc, 0, 0, 0);
      const int g = wv*64 + nf*16 + l15;
      #pragma unroll
      for (int r=0; r<4; r++){
        const int bs = bs0 + mf*16 + l4r*4 + r;
        const int s = bs % 20;
        out[bs*256 + g] = acc[r] + tg[s*256 + g];
      }
    }
  }
}

// ---------------- core relational MLP: 8-wave blocks, xf+af dbuf, setprio ----------------
// grid (512 b, 5 t) x 512 threads; X tile bf16 in LDS [80][264].
// LDS padded to 55.5KB -> 2 blocks/CU -> 4 waves/SIMD -> VGPR cap 128.
// xf register double-buffer across kk hides ~120cy LDS latency under MFMA cluster;
// af global prefetch crosses barriers (LBAR = LDS-only release); setprio on MFMA.
#define LDX 264
__global__ __launch_bounds__(512) void relnet_kernel(
    const float* __restrict__ pi, const float* __restrict__ pj, const float* __restrict__ qa,
    const u16* __restrict__ w2, const u16* __restrict__ w3, const u16* __restrict__ w4,
    const float* __restrict__ b2, const float* __restrict__ b3, const float* __restrict__ b4,
    float* __restrict__ sgp)
{
  __shared__ u16 Xs[80*LDX + 6656];   // pad -> 55552 B -> 2 blocks/CU
  const int tid = threadIdx.x;
  const int lane = tid & 63;
  const int wv  = tid >> 6;       // 0..7 -> h-range wv*32
  const int b   = blockIdx.x;
  const int t   = blockIdx.y;
  const int l15 = lane & 15;
  const int l4  = lane >> 4;

  const float* pib = pi + b*(20*256);
  const float* pjb = pj + b*(20*256);
  const float* qab = qa + b*256;

  const int ar0 = (wv*32 + l15)*256 + l4*8;        // af row offsets (hf=0/1)
  const int ar1 = (wv*32 + 16 + l15)*256 + l4*8;

  // ---- X1 = relu(pi + pj + qa) -> LDS bf16 ----
  #pragma unroll
  for (int it = 0; it < 5; ++it){
    int u  = it*512 + tid;
    int m  = u >> 5;
    int gq = (u & 31) << 3;
    int R  = t*80 + m;
    int i  = R / 20;
    int j  = R - i*20;
    const float4* pr = (const float4*)(pib + i*256 + gq);
    const float4* qr = (const float4*)(pjb + j*256 + gq);
    const float4* ar = (const float4*)(qab + gq);
    uint4 pk;
    {
      float4 a = pr[0], c4 = qr[0], d4 = ar[0];
      pk.x = pack2(fmaxf(a.x+c4.x+d4.x,0.f), fmaxf(a.y+c4.y+d4.y,0.f));
      pk.y = pack2(fmaxf(a.z+c4.z+d4.z,0.f), fmaxf(a.w+c4.w+d4.w,0.f));
    }
    {
      float4 a = pr[1], c4 = qr[1], d4 = ar[1];
      pk.z = pack2(fmaxf(a.x+c4.x+d4.x,0.f), fmaxf(a.y+c4.y+d4.y,0.f));
      pk.w = pack2(fmaxf(a.z+c4.z+d4.z,0.f), fmaxf(a.w+c4.w+d4.w,0.f));
    }
    *(uint4*)(&Xs[m*LDX + gq]) = pk;
  }

  // prefetch layer-0 kk=0 A-fragments (stay in flight across the barrier)
  short8 pf0 = *(const short8*)(w2 + ar0);
  short8 pf1 = *(const short8*)(w2 + ar1);

  LBAR();   // stage writes visible; no vmcnt drain

  // ---- layers 1,2 (g2,g3): X <- relu(W X^T + b) in place ----
  #pragma unroll
  for (int lay = 0; lay < 2; ++lay){
    const u16*   W    = lay ? w3 : w2;
    const u16*   Wn   = lay ? w4 : w3;
    const float* bias = lay ? b3 : b2;
    f32x4 acc[2][5];
    #pragma unroll
    for (int hf=0; hf<2; hf++)
      #pragma unroll
      for (int mf=0; mf<5; mf++)
        acc[hf][mf] = (f32x4){0.f,0.f,0.f,0.f};

    short8 xc[5];
    #pragma unroll
    for (int mf=0; mf<5; mf++)
      xc[mf] = *(const short8*)(&Xs[(mf*16 + l15)*LDX + l4*8]);

    #pragma unroll
    for (int kk = 0; kk < 8; ++kk){
      short8 a0 = pf0, a1 = pf1;
      const u16* src = (kk < 7) ? W : Wn;
      const int  kn  = (kk < 7) ? (kk+1)*32 : 0;
      pf0 = *(const short8*)(src + ar0 + kn);
      pf1 = *(const short8*)(src + ar1 + kn);
      short8 xn[5];
      if (kk < 7){
        #pragma unroll
        for (int mf=0; mf<5; mf++)
          xn[mf] = *(const short8*)(&Xs[(mf*16 + l15)*LDX + (kk+1)*32 + l4*8]);
      }
      __builtin_amdgcn_s_setprio(1);
      #pragma unroll
      for (int mf=0; mf<5; mf++){
        acc[0][mf] = __builtin_amdgcn_mfma_f32_16x16x32_bf16(a0, xc[mf], acc[0][mf], 0, 0, 0);
        acc[1][mf] = __builtin_amdgcn_mfma_f32_16x16x32_bf16(a1, xc[mf], acc[1][mf], 0, 0, 0);
      }
      __builtin_amdgcn_s_setprio(0);
      if (kk < 7){
        #pragma unroll
        for (int mf=0; mf<5; mf++) xc[mf] = xn[mf];
      }
    }

    LBAR();   // all reads of Xs complete (LDS only; pf0/pf1 remain in flight)
    #pragma unroll
    for (int hf=0; hf<2; hf++){
      int h0 = wv*32 + hf*16 + l4*4;
      float4 bi = *(const float4*)(bias + h0);
      #pragma unroll
      for (int mf=0; mf<5; mf++){
        int m = mf*16 + l15;
        uint2 pk;
        pk.x = pack2(fmaxf(acc[hf][mf][0]+bi.x,0.f), fmaxf(acc[hf][mf][1]+bi.y,0.f));
        pk.y = pack2(fmaxf(acc[hf][mf][2]+bi.z,0.f), fmaxf(acc[hf][mf][3]+bi.w,0.f));
        *(uint2*)(&Xs[m*LDX + h0]) = pk;
      }
    }
    LBAR();   // writes visible
  }

  // ---- layer 3 (g4) + column-sum epilogue (pf holds w4 kk=0) ----
  {
    f32x4 acc[2][5];
    #pragma unroll
    for (int hf=0; hf<2; hf++)
      #pragma unroll
      for (int mf=0; mf<5; mf++)
        acc[hf][mf] = (f32x4){0.f,0.f,0.f,0.f};

    short8 xc[5];
    #pragma unroll
    for (int mf=0; mf<5; mf++)
      xc[mf] = *(const short8*)(&Xs[(mf*16 + l15)*LDX + l4*8]);

    #pragma unroll
    for (int kk = 0; kk < 8; ++kk){
      short8 a0 = pf0, a1 = pf1;
      if (kk < 7){
        pf0 = *(const short8*)(w4 + ar0 + (kk+1)*32);
        pf1 = *(const short8*)(w4 + ar1 + (kk+1)*32);
      }
      short8 xn[5];
      if (kk < 7){
        #pragma unroll
        for (int mf=0; mf<5; mf++)
          xn[mf] = *(const short8*)(&Xs[(mf*16 + l15)*LDX + (kk+1)*32 + l4*8]);
      }
      __builtin_amdgcn_s_setprio(1);
      #pragma unroll
      for (int mf=0; mf<5; mf++){
        acc[0][mf] = __builtin_amdgcn_mfma_f32_16x16x32_bf16(a0, xc[mf], acc[0][mf], 0, 0, 0);
        acc[1][mf] = __builtin_amdgcn_mfma_f32_16x16x32_bf16(a1, xc[mf], acc[1][mf], 0, 0, 0);
      }
      __builtin_amdgcn_s_setprio(0);
      if (kk < 7){
        #pragma unroll
        for (int mf=0; mf<5; mf++) xc[mf] = xn[mf];
      }
    }

    #pragma unroll
    for (int hf=0; hf<2; hf++){
      int h0 = wv*32 + hf*16 + l4*4;
      float4 bi = *(const float4*)(b4 + h0);
      float s0 = 0.f, s1 = 0.f, s2 = 0.f, s3 = 0.f;
      #pragma unroll
      for (int mf=0; mf<5; mf++){
        s0 += fmaxf(acc[hf][mf][0]+bi.x,0.f);
        s1 += fmaxf(acc[hf][mf][1]+bi.y,0.f);
        s2 += fmaxf(acc[hf][mf][2]+bi.z,0.f);
        s3 += fmaxf(acc[hf][mf][3]+bi.w,0.f);
      }
      float sv[4] = {s0, s1, s2, s3};
      #pragma unroll
      for (int r=0; r<4; r++){
        float v = sv[r];
        v += __shfl_xor(v, 1);
        v += __shfl_xor(v, 2);
        v += __shfl_xor(v, 4);
        v += __shfl_xor(v, 8);
        if (l15 == 0){
          int h = h0 + r;
          // [t][b][h]: block-exclusive region -> no cross-XCD false sharing
          sgp[t*131072 + b*256 + h] = v;
        }
      }
    }
  }
}

// ---------------- f1 via MFMA, 5-way partial-sum folded into B-fragment load ----------------
__global__ __launch_bounds__(256) void fcm1_kernel(
    const float* __restrict__ sgp, const u16* __restrict__ w,
    const float* __restrict__ bias, u16* __restrict__ outp)
{
  const int tid = threadIdx.x, lane = tid & 63, wv = tid >> 6;
  const int l15 = lane & 15, l4 = lane >> 4;
  const int b0 = blockIdx.x*16;
  const int of0 = blockIdx.y*4 + wv;   // 0..15
  f32x4 acc = (f32x4){0.f,0.f,0.f,0.f};
  #pragma unroll
  for (int kk=0; kk<8; ++kk){
    const float* base = sgp + (b0+l15)*256 + kk*32 + l4*8;
    float4 s0 = {0.f,0.f,0.f,0.f}, s1 = {0.f,0.f,0.f,0.f};
    #pragma unroll
    for (int t=0;t<5;t++){
      float4 a = *(const float4*)(base + t*131072);
      float4 c = *(const float4*)(base + t*131072 + 4);
      s0.x += a.x; s0.y += a.y; s0.z += a.z; s0.w += a.w;
      s1.x += c.x; s1.y += c.y; s1.z += c.z; s1.w += c.w;
    }
    union { short8 s; u32 u[4]; } xf;
    xf.u[0] = pack2(s0.x, s0.y); xf.u[1] = pack2(s0.z, s0.w);
    xf.u[2] = pack2(s1.x, s1.y); xf.u[3] = pack2(s1.z, s1.w);
    short8 af = *(const short8*)(w + (of0*16 + l15)*256 + kk*32 + l4*8);
    acc = __builtin_amdgcn_mfma_f32_16x16x32_bf16(af, xf.s, acc, 0, 0, 0);
  }
  const int b = b0 + l15;
  const int o0 = of0*16 + l4*4;
  float v0 = fmaxf(acc[0] + bias[o0+0], 0.f);
  float v1 = fmaxf(acc[1] + bias[o0+1], 0.f);
  float v2 = fmaxf(acc[2] + bias[o0+2], 0.f);
  float v3 = fmaxf(acc[3] + bias[o0+3], 0.f);
  uint2 pk;
  pk.x = pack2(v0, v1);
  pk.y = pack2(v2, v3);
  *(uint2*)(outp + (size_t)b*256 + o0) = pk;
}

// ---------------- fc layers via MFMA (output sliced over blockIdx.y) ----------------
template<int HF, int KK, int OPAD, int OREAL, int MODE>
__global__ __launch_bounds__(256) void fcm_kernel(
    const u16* __restrict__ in, const u16* __restrict__ w,
    const float* __restrict__ bias, void* __restrict__ outp)
{
  const int K = KK*32;
  const int tid = threadIdx.x, lane = tid & 63, wv = tid >> 6;
  const int l15 = lane & 15, l4 = lane >> 4;
  const int b0 = blockIdx.x*16;
  const int of0 = (blockIdx.y*4 + wv)*HF;   // output fragment base
  f32x4 acc[HF];
  #pragma unroll
  for (int hf=0; hf<HF; hf++) acc[hf] = (f32x4){0.f,0.f,0.f,0.f};
  #pragma unroll 4
  for (int kk=0; kk<KK; ++kk){
    short8 xf = *(const short8*)(in + (b0+l15)*K + kk*32 + l4*8);
    #pragma unroll
    for (int hf=0; hf<HF; hf++){
      short8 af = *(const short8*)(w + ((of0+hf)*16 + l15)*K + kk*32 + l4*8);
      acc[hf] = __builtin_amdgcn_mfma_f32_16x16x32_bf16(af, xf, acc[hf], 0, 0, 0);
    }
  }
  const int b = b0 + l15;
  #pragma unroll
  for (int hf=0; hf<HF; hf++){
    const int o0 = (of0+hf)*16 + l4*4;
    float v[4];
    #pragma unroll
    for (int r=0;r<4;r++){
      float bv = (o0+r < OREAL) ? bias[o0+r] : 0.f;
      v[r] = acc[hf][r] + bv;
    }
    if (MODE == 0){
      uint2 pk;
      pk.x = pack2(fmaxf(v[0],0.f), fmaxf(v[1],0.f));
      pk.y = pack2(fmaxf(v[2],0.f), fmaxf(v[3],0.f));
      *(uint2*)((u16*)outp + (size_t)b*OPAD + o0) = pk;
    } else {
      float* of = (float*)outp;
      #pragma unroll
      for (int r=0;r<4;r++)
        if (o0+r < OREAL) of[(size_t)b*OREAL + o0 + r] = v[r];
    }
  }
}

// ---------------- launch ----------------
extern "C" void kernel_launch(void* const* d_in, const int* in_sizes, int n_in,
                              void* d_out, int out_size, void* d_ws, size_t ws_size,
                              hipStream_t stream)
{
  const int*   story    = (const int*)d_in[0];
  const int*   question = (const int*)d_in[1];
  const float* emb   = (const float*)d_in[2];
  const float* s_wih = (const float*)d_in[3];
  const float* s_whh = (const float*)d_in[4];
  const float* s_bih = (const float*)d_in[5];
  const float* s_bhh = (const float*)d_in[6];
  const float* q_wih = (const float*)d_in[7];
  const float* q_whh = (const float*)d_in[8];
  const float* q_bih = (const float*)d_in[9];
  const float* q_bhh = (const float*)d_in[10];
  const float* g1w = (const float*)d_in[11];
  const float* g1b = (const float*)d_in[12];
  const float* g2w = (const float*)d_in[13];
  const float* g2b = (const float*)d_in[14];
  const float* g3w = (const float*)d_in[15];
  const float* g3b = (const float*)d_in[16];
  const float* g4w = (const float*)d_in[17];
  const float* g4b = (const float*)d_in[18];
  const float* f1w = (const float*)d_in[19];
  const float* f1b = (const float*)d_in[20];
  const float* f2w = (const float*)d_in[21];
  const float* f2b = (const float*)d_in[22];
  const float* f3w = (const float*)d_in[23];
  const float* f3b = (const float*)d_in[24];

  float* ws  = (float*)d_ws;
  float* xps = ws + OFF_XPS;
  float* xpq = ws + OFF_XPQ;
  float* qst = ws + OFF_QST;
  float* pi  = ws + OFF_PI;
  float* pj  = ws + OFF_PJ;
  float* qa  = ws + OFF_QA;
  float* tga = ws + OFF_TGA;
  float* tgb = ws + OFF_TGB;
  float* sgp = ws + OFF_SGP;
  u16*   wb    = (u16*)(ws + OFF_WB);
  u16*   w2b   = wb;
  u16*   w3b   = wb + 65536;
  u16*   w4b   = wb + 131072;
  u16*   stb   = (u16*)(ws + OFF_STB);
  u16*   wab   = (u16*)(ws + OFF_WAB);
  u16*   wbb   = (u16*)(ws + OFF_WBB);
  u16*   whhbs = (u16*)(ws + OFF_WHHS);
  u16*   whhbq = (u16*)(ws + OFF_WHHQ);
  u16*   wf1   = (u16*)(ws + OFF_WF1);
  u16*   wf2   = (u16*)(ws + OFF_WF2);
  u16*   wf3   = (u16*)(ws + OFF_WF3);
  u16*   act1  = (u16*)(ws + OFF_ACT1);
  u16*   act2  = (u16*)(ws + OFF_ACT2);

  prep_kernel<<<dim3(160,3), dim3(256), 0, stream>>>(
      emb, s_wih, s_bih, s_bhh, q_wih, q_bih, q_bhh,
      g2w, g3w, g4w, g1w, s_whh, q_whh, f1w, f2w, f3w,
      xps, xpq, wb, wab, wbb, tga, tgb, whhbs, whhbq, wf1, wf2, wf3);
  lstm_kernel<<<dim3(672), dim3(64), 0, stream>>>(
      story, question, xps, xpq, whhbs, whhbq, stb, qst);
  pipj_kernel<<<dim3(160,3), dim3(256), 0, stream>>>(
      stb, wab, wbb, tga, tgb, qst, g1w, g1b, pi, pj, qa);
  relnet_kernel<<<dim3(512,5), dim3(512), 0, stream>>>(
      pi, pj, qa, w2b, w3b, w4b, g2b, g3b, g4b, sgp);
  fcm1_kernel<<<dim3(32,4), dim3(256), 0, stream>>>(sgp, wf1, f1b, act1);
  fcm_kernel<2,8,512,512,0><<<dim3(32,4), dim3(256), 0, stream>>>(act1, wf2, f2b, act2);
  fcm_kernel<2,16,1024,1000,1><<<dim3(32,8), dim3(256), 0, stream>>>(act2, wf3, f3b, (float*)d_out);
}

// Round 14
// 202.658 us; speedup vs baseline: 1.5283x; 1.1429x over previous
//
#include <hip/hip_runtime.h>

typedef unsigned short u16;
typedef unsigned int   u32;
typedef __attribute__((ext_vector_type(8))) short short8;
typedef __attribute__((ext_vector_type(4))) float f32x4;

// ---------------- ws layout (float element offsets) ----------------
#define OFF_XPS   0            // 10000*128 (gate-permuted xp story)
#define OFF_XPQ   1280000      // 10000*128 (gate-permuted xp question)
#define OFF_QST   2560000      // 512*32
#define OFF_PI    2576384      // 512*20*256
#define OFF_PJ    5197824      // 512*20*256
#define OFF_QA    7819264      // 512*256
#define OFF_TGA   7950336      // 20*256
#define OFF_TGB   7955456      // 20*256
#define OFF_WB    7960576      // u16 x 196608 (g2/g3/g4 bf16)
#define OFF_STB   8058880      // u16 x 327680 (story h bf16)
#define OFF_WAB   8222720      // u16 x 8192
#define OFF_WBB   8226816      // u16 x 8192
#define OFF_WHHS  8230912      // u16 x 4096
#define OFF_WHHQ  8232960      // u16 x 4096
#define OFF_WF1   8235008      // u16 x 65536
#define OFF_WF2   8267776      // u16 x 131072
#define OFF_WF3   8333312      // u16 x 524288 (1024x512, zero-padded)
// aliased into XPS/XPQ region (dead after lstm):
#define OFF_SGP   0            // 5*256*512 fl  [t][b][h]
#define OFF_ACT1  720896       // u16 x 131072 ([b][256])
#define OFF_ACT2  786432       // u16 x 262144 ([b][512])

__device__ __forceinline__ u16 f2bf(float f){
  union { float f; u32 u; } v; v.f = f;
  u32 u = v.u;
  u32 r = u + 0x7fffu + ((u >> 16) & 1u);
  return (u16)(r >> 16);
}
__device__ __forceinline__ u32 pack2(float a, float b){
  u32 r;
  asm("v_cvt_pk_bf16_f32 %0, %1, %2" : "=v"(r) : "v"(a), "v"(b));
  return r;
}
__device__ __forceinline__ float sigm(float x){
  return __builtin_amdgcn_rcpf(1.f + __expf(-x));
}

// LDS-only release barrier: no vmcnt drain.
#define LBAR() do {                                        \
    asm volatile("s_waitcnt lgkmcnt(0)" ::: "memory");     \
    __builtin_amdgcn_s_barrier();                          \
    __builtin_amdgcn_sched_barrier(0);                     \
  } while (0)

// ---------------- prep: xp tables (y=0,1; g-split over x) + misc (y=2) ----------------
__global__ __launch_bounds__(256) void prep_kernel(
    const float* __restrict__ emb,
    const float* __restrict__ swih, const float* __restrict__ sbih, const float* __restrict__ sbhh,
    const float* __restrict__ qwih, const float* __restrict__ qbih, const float* __restrict__ qbhh,
    const float* __restrict__ g2w, const float* __restrict__ g3w, const float* __restrict__ g4w,
    const float* __restrict__ g1w,
    const float* __restrict__ swhh, const float* __restrict__ qwhh,
    const float* __restrict__ f1w, const float* __restrict__ f2w, const float* __restrict__ f3w,
    float* __restrict__ xps, float* __restrict__ xpq,
    u16* __restrict__ wb, u16* __restrict__ wab, u16* __restrict__ wbb,
    float* __restrict__ tga, float* __restrict__ tgb,
    u16* __restrict__ whhbs, u16* __restrict__ whhbq,
    u16* __restrict__ wf1, u16* __restrict__ wf2, u16* __restrict__ wf3)
{
  __shared__ float wl[2048];
  __shared__ float bl[64];
  const int tid = threadIdx.x;
  if (blockIdx.y == 2){
    const int B = 196608;
    const int C = B + 16384;
    const int D = C + 10240;
    const int E = D + 8192;
    const int F = E + 65536;
    const int G = F + 131072;
    const int H = G + 524288;
    for (int idx = blockIdx.x*256 + tid; idx < H; idx += 160*256){
      if (idx < B){
        const int k = idx;
        const float* src = (k < 65536) ? g2w : ((k < 131072) ? g3w : g4w);
        wb[k] = f2bf(src[k & 65535]);
      } else if (idx < C){
        const int k = idx - B;
        if (k < 8192) wab[k] = f2bf(g1w[(k>>5)*136 + (k&31)]);
        else { const int k2 = k - 8192; wbb[k2] = f2bf(g1w[(k2>>5)*136 + 52 + (k2&31)]); }
      } else if (idx < D){
        const int k = idx - C;
        if (k < 5120){ const int s = k >> 8, g = k & 255; tga[k] = g1w[g*136 + 32 + s]; }
        else { const int k2 = k - 5120; const int s = k2 >> 8, g = k2 & 255; tgb[k2] = g1w[g*136 + 84 + s]; }
      } else if (idx < E){
        const int k = idx - D;
        if (k < 4096) whhbs[k] = f2bf(swhh[k]);
        else whhbq[k-4096] = f2bf(qwhh[k-4096]);
      } else if (idx < F){
        const int k = idx - E;
        wf1[k] = f2bf(f1w[k]);
      } else if (idx < G){
        const int k = idx - F;
        wf2[k] = f2bf(f2w[k]);
      } else {
        const int k = idx - G;
        const int o = k >> 9, kk = k & 511;
        wf3[k] = (o < 1000) ? f2bf(f3w[o*512 + kk]) : (u16)0;
      }
    }
    return;
  }
  if (blockIdx.x >= 80) return;
  const bool isq = blockIdx.y;
  const float* wih = isq ? qwih : swih;
  const float* bih = isq ? qbih : sbih;
  const float* bhh = isq ? qbhh : sbhh;
  float* xp = isq ? xpq : xps;
  const int gh = (blockIdx.x & 1) * 64;   // g-half this block computes
  #pragma unroll
  for (int k=0;k<8;k++) wl[k*256+tid] = wih[gh*32 + k*256 + tid];
  if (tid < 64) bl[tid] = bih[gh+tid] + bhh[gh+tid];
  __syncthreads();
  const int v = (blockIdx.x >> 1)*256 + tid;
  if (v >= 10000) return;
  float4 e[8];
  #pragma unroll
  for (int q=0;q<8;q++) e[q] = *(const float4*)(emb + v*32 + q*4);
  for (int g2=0; g2<64; ++g2){
    const int g = gh + g2;
    float acc = bl[g2];
    #pragma unroll
    for (int q=0;q<8;q++){
      float4 w4 = *(const float4*)(&wl[g2*32 + q*4]);
      acc = fmaf(e[q].x, w4.x, acc); acc = fmaf(e[q].y, w4.y, acc);
      acc = fmaf(e[q].z, w4.z, acc); acc = fmaf(e[q].w, w4.w, acc);
    }
    xp[v*128 + (g&15)*8 + (g>>4)] = acc;
  }
}

// ---------------- LSTM via MFMA: 16 sequences per wave ----------------
template<int LEN>
__device__ __forceinline__ void lstm_mfma_run(
    const int* __restrict__ toks, int s0,
    const float* __restrict__ xpr, const u16* __restrict__ whhb,
    u16* __restrict__ hl, int lane, float* h0r, float* h1r)
{
  const int l15 = lane & 15, l4 = lane >> 4;
  short8 wf[8];
  #pragma unroll
  for (int f=0; f<8; f++)
    wf[f] = *(const short8*)(whhb + (f*16+l15)*32 + l4*8);
  short8 ha = (short8){0,0,0,0,0,0,0,0};
  float c0[4] = {0,0,0,0}, c1[4] = {0,0,0,0};
  int tk[4];
  #pragma unroll
  for (int r=0;r<4;r++) tk[r] = toks[(s0 + l4*4 + r)*LEN];
  float4 xa[4], xb[4];
  #pragma unroll
  for (int r=0;r<4;r++){
    xa[r] = *(const float4*)(xpr + tk[r]*128 + l15*8);
    xb[r] = *(const float4*)(xpr + tk[r]*128 + l15*8 + 4);
  }
  #pragma unroll
  for (int t=0; t<LEN; ++t){
    int tkn[4];
    if (t+1 < LEN){
      #pragma unroll
      for (int r=0;r<4;r++) tkn[r] = toks[(s0 + l4*4 + r)*LEN + t + 1];
    }
    const f32x4 z = (f32x4){0.f,0.f,0.f,0.f};
    f32x4 acc[8];
    #pragma unroll
    for (int f=0; f<8; f++)
      acc[f] = __builtin_amdgcn_mfma_f32_16x16x32_bf16(ha, wf[f], z, 0, 0, 0);
    float4 na[4], nb[4];
    if (t+1 < LEN){
      #pragma unroll
      for (int r=0;r<4;r++){
        na[r] = *(const float4*)(xpr + tkn[r]*128 + l15*8);
        nb[r] = *(const float4*)(xpr + tkn[r]*128 + l15*8 + 4);
      }
    }
    #pragma unroll
    for (int r=0;r<4;r++){
      float i0 = sigm(acc[0][r] + xa[r].x);
      float f0 = sigm(acc[2][r] + xa[r].z);
      float g0 = 2.f*sigm(2.f*(acc[4][r] + xb[r].x)) - 1.f;
      float o0 = sigm(acc[6][r] + xb[r].z);
      c0[r] = fmaf(f0, c0[r], i0*g0);
      h0r[r] = o0 * (2.f*sigm(2.f*c0[r]) - 1.f);
      float i1 = sigm(acc[1][r] + xa[r].y);
      float f1v = sigm(acc[3][r] + xa[r].w);
      float g1v = 2.f*sigm(2.f*(acc[5][r] + xb[r].y)) - 1.f;
      float o1 = sigm(acc[7][r] + xb[r].w);
      c1[r] = fmaf(f1v, c1[r], i1*g1v);
      h1r[r] = o1 * (2.f*sigm(2.f*c1[r]) - 1.f);
    }
    if (t+1 < LEN){
      #pragma unroll
      for (int r=0;r<4;r++){
        hl[(l4*4+r)*32 + l15]      = f2bf(h0r[r]);
        hl[(l4*4+r)*32 + 16 + l15] = f2bf(h1r[r]);
      }
      __syncthreads();
      ha = *(const short8*)(hl + l15*32 + l4*8);
      #pragma unroll
      for (int r=0;r<4;r++){ xa[r] = na[r]; xb[r] = nb[r]; }
    }
  }
}

__global__ __launch_bounds__(64) void lstm_kernel(
    const int* __restrict__ story, const int* __restrict__ question,
    const float* __restrict__ xprs, const float* __restrict__ xprq,
    const u16* __restrict__ whhbs, const u16* __restrict__ whhbq,
    u16* __restrict__ stb, float* __restrict__ qst)
{
  __shared__ u16 hl[512];
  const int lane = threadIdx.x;
  const int w = blockIdx.x;
  const int l15 = lane & 15, l4 = lane >> 4;
  float h0r[4], h1r[4];
  if (w >= 640){
    const int s0 = (w - 640)*16;
    lstm_mfma_run<16>(question, s0, xprq, whhbq, hl, lane, h0r, h1r);
    #pragma unroll
    for (int r=0;r<4;r++){
      qst[(s0 + l4*4 + r)*32 + l15]      = h0r[r];
      qst[(s0 + l4*4 + r)*32 + 16 + l15] = h1r[r];
    }
  } else {
    const int s0 = w*16;
    lstm_mfma_run<32>(story, s0, xprs, whhbs, hl, lane, h0r, h1r);
    #pragma unroll
    for (int r=0;r<4;r++){
      stb[(s0 + l4*4 + r)*32 + l15]      = f2bf(h0r[r]);
      stb[(s0 + l4*4 + r)*32 + 16 + l15] = f2bf(h1r[r]);
    }
  }
}

// ---------------- pi / pj via MFMA (K=32, one step); y==2 computes qa ----------------
__global__ __launch_bounds__(256) void pipj_kernel(
    const u16* __restrict__ stb, const u16* __restrict__ wab, const u16* __restrict__ wbb,
    const float* __restrict__ tga, const float* __restrict__ tgb,
    const float* __restrict__ qst, const float* __restrict__ g1w, const float* __restrict__ g1b,
    float* __restrict__ pi, float* __restrict__ pj, float* __restrict__ qa)
{
  const int tid = threadIdx.x;
  if (blockIdx.y == 2){
    for (int idx = blockIdx.x*256 + tid; idx < 131072; idx += 160*256){
      const int b = idx >> 8, g = idx & 255;
      const float* qs = qst + b*32;
      const float* wr = g1w + g*136 + 104;
      float acc = g1b[g];
      #pragma unroll
      for (int q=0;q<8;q++){
        float4 s4 = *(const float4*)(qs + q*4);
        float4 w4 = *(const float4*)(wr + q*4);
        acc = fmaf(s4.x, w4.x, acc); acc = fmaf(s4.y, w4.y, acc);
        acc = fmaf(s4.z, w4.z, acc); acc = fmaf(s4.w, w4.w, acc);
      }
      qa[idx] = acc;
    }
    return;
  }
  const int lane = tid & 63;
  const int wv = tid >> 6;
  const int l15 = lane & 15;
  const int l4r = lane >> 4;
  const int bs0 = blockIdx.x * 64;
  const bool isj = blockIdx.y;
  const u16* wB = isj ? wbb : wab;
  const float* tg = isj ? tgb : tga;
  float* out = isj ? pj : pi;

  short8 af[4], bf[4];
  #pragma unroll
  for (int mf=0; mf<4; mf++)
    af[mf] = *(const short8*)(stb + (bs0 + mf*16 + l15)*32 + l4r*8);
  #pragma unroll
  for (int nf=0; nf<4; nf++)
    bf[nf] = *(const short8*)(wB + (wv*64 + nf*16 + l15)*32 + l4r*8);

  #pragma unroll
  for (int mf=0; mf<4; mf++){
    #pragma unroll
    for (int nf=0; nf<4; nf++){
      f32x4 acc = (f32x4){0.f,0.f,0.f,0.f};
      acc = __builtin_amdgcn_mfma_f32_16x16x32_bf16(af[mf], bf[nf], acc, 0, 0, 0);
      const int g = wv*64 + nf*16 + l15;
      #pragma unroll
      for (int r=0; r<4; r++){
        const int bs = bs0 + mf*16 + l4r*4 + r;
        const int s = bs % 20;
        out[bs*256 + g] = acc[r] + tg[s*256 + g];
      }
    }
  }
}

// ---------------- core relational MLP: DUAL-TILE per block ----------------
// grid (256 b-pairs, 5 t) x 512 threads; two independent X tiles (b=2x, 2x+1)
// in LDS, fused per-kk: {xfA read || mfmaB} interleave gives per-wave ILP,
// af W-loads shared between tiles (half the af traffic), each barrier
// amortized over 2x work. LDS 84.5KB -> 1 block/CU, 8 waves, VGPR cap 256.
#define LDX 264
__global__ __launch_bounds__(512) void relnet_kernel(
    const float* __restrict__ pi, const float* __restrict__ pj, const float* __restrict__ qa,
    const u16* __restrict__ w2, const u16* __restrict__ w3, const u16* __restrict__ w4,
    const float* __restrict__ b2, const float* __restrict__ b3, const float* __restrict__ b4,
    float* __restrict__ sgp)
{
  __shared__ u16 Xs[2][80*LDX];   // 84480 B -> 1 block/CU
  const int tid = threadIdx.x;
  const int lane = tid & 63;
  const int wv  = tid >> 6;       // 0..7 -> h-range wv*32
  const int bA  = blockIdx.x*2;
  const int t   = blockIdx.y;
  const int l15 = lane & 15;
  const int l4  = lane >> 4;

  const int ar0 = (wv*32 + l15)*256 + l4*8;        // af row offsets (hf=0/1)
  const int ar1 = (wv*32 + 16 + l15)*256 + l4*8;

  // ---- stage both tiles: X1 = relu(pi + pj + qa) -> LDS bf16 ----
  #pragma unroll
  for (int s = 0; s < 2; ++s){
    const float* pib = pi + (bA+s)*(20*256);
    const float* pjb = pj + (bA+s)*(20*256);
    const float* qab = qa + (bA+s)*256;
    #pragma unroll
    for (int it = 0; it < 5; ++it){
      int u  = it*512 + tid;
      int m  = u >> 5;
      int gq = (u & 31) << 3;
      int R  = t*80 + m;
      int i  = R / 20;
      int j  = R - i*20;
      const float4* pr = (const float4*)(pib + i*256 + gq);
      const float4* qr = (const float4*)(pjb + j*256 + gq);
      const float4* ar = (const float4*)(qab + gq);
      uint4 pk;
      {
        float4 a = pr[0], c4 = qr[0], d4 = ar[0];
        pk.x = pack2(fmaxf(a.x+c4.x+d4.x,0.f), fmaxf(a.y+c4.y+d4.y,0.f));
        pk.y = pack2(fmaxf(a.z+c4.z+d4.z,0.f), fmaxf(a.w+c4.w+d4.w,0.f));
      }
      {
        float4 a = pr[1], c4 = qr[1], d4 = ar[1];
        pk.z = pack2(fmaxf(a.x+c4.x+d4.x,0.f), fmaxf(a.y+c4.y+d4.y,0.f));
        pk.w = pack2(fmaxf(a.z+c4.z+d4.z,0.f), fmaxf(a.w+c4.w+d4.w,0.f));
      }
      *(uint4*)(&Xs[s][m*LDX + gq]) = pk;
    }
  }
  LBAR();

  // ---- layers 1,2 (g2,g3): X <- relu(W X^T + b) in place, both tiles ----
  #pragma unroll
  for (int lay = 0; lay < 2; ++lay){
    const u16*   W    = lay ? w3 : w2;
    const float* bias = lay ? b3 : b2;
    f32x4 aA[2][5], aB[2][5];
    #pragma unroll
    for (int hf=0; hf<2; hf++)
      #pragma unroll
      for (int mf=0; mf<5; mf++){
        aA[hf][mf] = (f32x4){0.f,0.f,0.f,0.f};
        aB[hf][mf] = (f32x4){0.f,0.f,0.f,0.f};
      }

    #pragma unroll
    for (int kk = 0; kk < 8; ++kk){
      short8 w0 = *(const short8*)(W + ar0 + kk*32);
      short8 w1 = *(const short8*)(W + ar1 + kk*32);
      short8 xA[5], xB[5];
      #pragma unroll
      for (int mf=0; mf<5; mf++)
        xA[mf] = *(const short8*)(&Xs[0][(mf*16 + l15)*LDX + kk*32 + l4*8]);
      #pragma unroll
      for (int mf=0; mf<5; mf++)
        xB[mf] = *(const short8*)(&Xs[1][(mf*16 + l15)*LDX + kk*32 + l4*8]);
      #pragma unroll
      for (int mf=0; mf<5; mf++){
        aA[0][mf] = __builtin_amdgcn_mfma_f32_16x16x32_bf16(w0, xA[mf], aA[0][mf], 0, 0, 0);
        aA[1][mf] = __builtin_amdgcn_mfma_f32_16x16x32_bf16(w1, xA[mf], aA[1][mf], 0, 0, 0);
      }
      #pragma unroll
      for (int mf=0; mf<5; mf++){
        aB[0][mf] = __builtin_amdgcn_mfma_f32_16x16x32_bf16(w0, xB[mf], aB[0][mf], 0, 0, 0);
        aB[1][mf] = __builtin_amdgcn_mfma_f32_16x16x32_bf16(w1, xB[mf], aB[1][mf], 0, 0, 0);
      }
    }

    LBAR();   // all reads of both tiles complete
    #pragma unroll
    for (int hf=0; hf<2; hf++){
      int h0 = wv*32 + hf*16 + l4*4;
      float4 bi = *(const float4*)(bias + h0);
      #pragma unroll
      for (int mf=0; mf<5; mf++){
        int m = mf*16 + l15;
        uint2 pkA, pkB;
        pkA.x = pack2(fmaxf(aA[hf][mf][0]+bi.x,0.f), fmaxf(aA[hf][mf][1]+bi.y,0.f));
        pkA.y = pack2(fmaxf(aA[hf][mf][2]+bi.z,0.f), fmaxf(aA[hf][mf][3]+bi.w,0.f));
        *(uint2*)(&Xs[0][m*LDX + h0]) = pkA;
        pkB.x = pack2(fmaxf(aB[hf][mf][0]+bi.x,0.f), fmaxf(aB[hf][mf][1]+bi.y,0.f));
        pkB.y = pack2(fmaxf(aB[hf][mf][2]+bi.z,0.f), fmaxf(aB[hf][mf][3]+bi.w,0.f));
        *(uint2*)(&Xs[1][m*LDX + h0]) = pkB;
      }
    }
    LBAR();   // writes visible
  }

  // ---- layer 3 (g4) + column-sum epilogue, both tiles ----
  {
    f32x4 aA[2][5], aB[2][5];
    #pragma unroll
    for (int hf=0; hf<2; hf++)
      #pragma unroll
      for (int mf=0; mf<5; mf++){
        aA[hf][mf] = (f32x4){0.f,0.f,0.f,0.f};
        aB[hf][mf] = (f32x4){0.f,0.f,0.f,0.f};
      }

    #pragma unroll
    for (int kk = 0; kk < 8; ++kk){
      short8 w0 = *(const short8*)(w4 + ar0 + kk*32);
      short8 w1 = *(const short8*)(w4 + ar1 + kk*32);
      short8 xA[5], xB[5];
      #pragma unroll
      for (int mf=0; mf<5; mf++)
        xA[mf] = *(const short8*)(&Xs[0][(mf*16 + l15)*LDX + kk*32 + l4*8]);
      #pragma unroll
      for (int mf=0; mf<5; mf++)
        xB[mf] = *(const short8*)(&Xs[1][(mf*16 + l15)*LDX + kk*32 + l4*8]);
      #pragma unroll
      for (int mf=0; mf<5; mf++){
        aA[0][mf] = __builtin_amdgcn_mfma_f32_16x16x32_bf16(w0, xA[mf], aA[0][mf], 0, 0, 0);
        aA[1][mf] = __builtin_amdgcn_mfma_f32_16x16x32_bf16(w1, xA[mf], aA[1][mf], 0, 0, 0);
      }
      #pragma unroll
      for (int mf=0; mf<5; mf++){
        aB[0][mf] = __builtin_amdgcn_mfma_f32_16x16x32_bf16(w0, xB[mf], aB[0][mf], 0, 0, 0);
        aB[1][mf] = __builtin_amdgcn_mfma_f32_16x16x32_bf16(w1, xB[mf], aB[1][mf], 0, 0, 0);
      }
    }

    #pragma unroll
    for (int hf=0; hf<2; hf++){
      int h0 = wv*32 + hf*16 + l4*4;
      float4 bi = *(const float4*)(b4 + h0);
      float sA[4] = {0.f,0.f,0.f,0.f};
      float sB[4] = {0.f,0.f,0.f,0.f};
      #pragma unroll
      for (int mf=0; mf<5; mf++){
        sA[0] += fmaxf(aA[hf][mf][0]+bi.x,0.f);
        sA[1] += fmaxf(aA[hf][mf][1]+bi.y,0.f);
        sA[2] += fmaxf(aA[hf][mf][2]+bi.z,0.f);
        sA[3] += fmaxf(aA[hf][mf][3]+bi.w,0.f);
        sB[0] += fmaxf(aB[hf][mf][0]+bi.x,0.f);
        sB[1] += fmaxf(aB[hf][mf][1]+bi.y,0.f);
        sB[2] += fmaxf(aB[hf][mf][2]+bi.z,0.f);
        sB[3] += fmaxf(aB[hf][mf][3]+bi.w,0.f);
      }
      #pragma unroll
      for (int r=0; r<4; r++){
        float vA = sA[r];
        vA += __shfl_xor(vA, 1);
        vA += __shfl_xor(vA, 2);
        vA += __shfl_xor(vA, 4);
        vA += __shfl_xor(vA, 8);
        float vB = sB[r];
        vB += __shfl_xor(vB, 1);
        vB += __shfl_xor(vB, 2);
        vB += __shfl_xor(vB, 4);
        vB += __shfl_xor(vB, 8);
        if (l15 == 0){
          int h = h0 + r;
          sgp[t*131072 + bA*256 + h]       = vA;
          sgp[t*131072 + (bA+1)*256 + h]   = vB;
        }
      }
    }
  }
}

// ---------------- f1 via MFMA, 5-way partial-sum folded into B-fragment load ----------------
__global__ __launch_bounds__(256) void fcm1_kernel(
    const float* __restrict__ sgp, const u16* __restrict__ w,
    const float* __restrict__ bias, u16* __restrict__ outp)
{
  const int tid = threadIdx.x, lane = tid & 63, wv = tid >> 6;
  const int l15 = lane & 15, l4 = lane >> 4;
  const int b0 = blockIdx.x*16;
  const int of0 = blockIdx.y*4 + wv;   // 0..15
  f32x4 acc = (f32x4){0.f,0.f,0.f,0.f};
  #pragma unroll
  for (int kk=0; kk<8; ++kk){
    const float* base = sgp + (b0+l15)*256 + kk*32 + l4*8;
    float4 s0 = {0.f,0.f,0.f,0.f}, s1 = {0.f,0.f,0.f,0.f};
    #pragma unroll
    for (int t=0;t<5;t++){
      float4 a = *(const float4*)(base + t*131072);
      float4 c = *(const float4*)(base + t*131072 + 4);
      s0.x += a.x; s0.y += a.y; s0.z += a.z; s0.w += a.w;
      s1.x += c.x; s1.y += c.y; s1.z += c.z; s1.w += c.w;
    }
    union { short8 s; u32 u[4]; } xf;
    xf.u[0] = pack2(s0.x, s0.y); xf.u[1] = pack2(s0.z, s0.w);
    xf.u[2] = pack2(s1.x, s1.y); xf.u[3] = pack2(s1.z, s1.w);
    short8 af = *(const short8*)(w + (of0*16 + l15)*256 + kk*32 + l4*8);
    acc = __builtin_amdgcn_mfma_f32_16x16x32_bf16(af, xf.s, acc, 0, 0, 0);
  }
  const int b = b0 + l15;
  const int o0 = of0*16 + l4*4;
  float v0 = fmaxf(acc[0] + bias[o0+0], 0.f);
  float v1 = fmaxf(acc[1] + bias[o0+1], 0.f);
  float v2 = fmaxf(acc[2] + bias[o0+2], 0.f);
  float v3 = fmaxf(acc[3] + bias[o0+3], 0.f);
  uint2 pk;
  pk.x = pack2(v0, v1);
  pk.y = pack2(v2, v3);
  *(uint2*)(outp + (size_t)b*256 + o0) = pk;
}

// ---------------- fc layers via MFMA (output sliced over blockIdx.y) ----------------
template<int HF, int KK, int OPAD, int OREAL, int MODE>
__global__ __launch_bounds__(256) void fcm_kernel(
    const u16* __restrict__ in, const u16* __restrict__ w,
    const float* __restrict__ bias, void* __restrict__ outp)
{
  const int K = KK*32;
  const int tid = threadIdx.x, lane = tid & 63, wv = tid >> 6;
  const int l15 = lane & 15, l4 = lane >> 4;
  const int b0 = blockIdx.x*16;
  const int of0 = (blockIdx.y*4 + wv)*HF;   // output fragment base
  f32x4 acc[HF];
  #pragma unroll
  for (int hf=0; hf<HF; hf++) acc[hf] = (f32x4){0.f,0.f,0.f,0.f};
  #pragma unroll 4
  for (int kk=0; kk<KK; ++kk){
    short8 xf = *(const short8*)(in + (b0+l15)*K + kk*32 + l4*8);
    #pragma unroll
    for (int hf=0; hf<HF; hf++){
      short8 af = *(const short8*)(w + ((of0+hf)*16 + l15)*K + kk*32 + l4*8);
      acc[hf] = __builtin_amdgcn_mfma_f32_16x16x32_bf16(af, xf, acc[hf], 0, 0, 0);
    }
  }
  const int b = b0 + l15;
  #pragma unroll
  for (int hf=0; hf<HF; hf++){
    const int o0 = (of0+hf)*16 + l4*4;
    float v[4];
    #pragma unroll
    for (int r=0;r<4;r++){
      float bv = (o0+r < OREAL) ? bias[o0+r] : 0.f;
      v[r] = acc[hf][r] + bv;
    }
    if (MODE == 0){
      uint2 pk;
      pk.x = pack2(fmaxf(v[0],0.f), fmaxf(v[1],0.f));
      pk.y = pack2(fmaxf(v[2],0.f), fmaxf(v[3],0.f));
      *(uint2*)((u16*)outp + (size_t)b*OPAD + o0) = pk;
    } else {
      float* of = (float*)outp;
      #pragma unroll
      for (int r=0;r<4;r++)
        if (o0+r < OREAL) of[(size_t)b*OREAL + o0 + r] = v[r];
    }
  }
}

// ---------------- launch ----------------
extern "C" void kernel_launch(void* const* d_in, const int* in_sizes, int n_in,
                              void* d_out, int out_size, void* d_ws, size_t ws_size,
                              hipStream_t stream)
{
  const int*   story    = (const int*)d_in[0];
  const int*   question = (const int*)d_in[1];
  const float* emb   = (const float*)d_in[2];
  const float* s_wih = (const float*)d_in[3];
  const float* s_whh = (const float*)d_in[4];
  const float* s_bih = (const float*)d_in[5];
  const float* s_bhh = (const float*)d_in[6];
  const float* q_wih = (const float*)d_in[7];
  const float* q_whh = (const float*)d_in[8];
  const float* q_bih = (const float*)d_in[9];
  const float* q_bhh = (const float*)d_in[10];
  const float* g1w = (const float*)d_in[11];
  const float* g1b = (const float*)d_in[12];
  const float* g2w = (const float*)d_in[13];
  const float* g2b = (const float*)d_in[14];
  const float* g3w = (const float*)d_in[15];
  const float* g3b = (const float*)d_in[16];
  const float* g4w = (const float*)d_in[17];
  const float* g4b = (const float*)d_in[18];
  const float* f1w = (const float*)d_in[19];
  const float* f1b = (const float*)d_in[20];
  const float* f2w = (const float*)d_in[21];
  const float* f2b = (const float*)d_in[22];
  const float* f3w = (const float*)d_in[23];
  const float* f3b = (const float*)d_in[24];

  float* ws  = (float*)d_ws;
  float* xps = ws + OFF_XPS;
  float* xpq = ws + OFF_XPQ;
  float* qst = ws + OFF_QST;
  float* pi  = ws + OFF_PI;
  float* pj  = ws + OFF_PJ;
  float* qa  = ws + OFF_QA;
  float* tga = ws + OFF_TGA;
  float* tgb = ws + OFF_TGB;
  float* sgp = ws + OFF_SGP;
  u16*   wb    = (u16*)(ws + OFF_WB);
  u16*   w2b   = wb;
  u16*   w3b   = wb + 65536;
  u16*   w4b   = wb + 131072;
  u16*   stb   = (u16*)(ws + OFF_STB);
  u16*   wab   = (u16*)(ws + OFF_WAB);
  u16*   wbb   = (u16*)(ws + OFF_WBB);
  u16*   whhbs = (u16*)(ws + OFF_WHHS);
  u16*   whhbq = (u16*)(ws + OFF_WHHQ);
  u16*   wf1   = (u16*)(ws + OFF_WF1);
  u16*   wf2   = (u16*)(ws + OFF_WF2);
  u16*   wf3   = (u16*)(ws + OFF_WF3);
  u16*   act1  = (u16*)(ws + OFF_ACT1);
  u16*   act2  = (u16*)(ws + OFF_ACT2);

  prep_kernel<<<dim3(160,3), dim3(256), 0, stream>>>(
      emb, s_wih, s_bih, s_bhh, q_wih, q_bih, q_bhh,
      g2w, g3w, g4w, g1w, s_whh, q_whh, f1w, f2w, f3w,
      xps, xpq, wb, wab, wbb, tga, tgb, whhbs, whhbq, wf1, wf2, wf3);
  lstm_kernel<<<dim3(672), dim3(64), 0, stream>>>(
      story, question, xps, xpq, whhbs, whhbq, stb, qst);
  pipj_kernel<<<dim3(160,3), dim3(256), 0, stream>>>(
      stb, wab, wbb, tga, tgb, qst, g1w, g1b, pi, pj, qa);
  relnet_kernel<<<dim3(256,5), dim3(512), 0, stream>>>(
      pi, pj, qa, w2b, w3b, w4b, g2b, g3b, g4b, sgp);
  fcm1_kernel<<<dim3(32,4), dim3(256), 0, stream>>>(sgp, wf1, f1b, act1);
  fcm_kernel<2,8,512,512,0><<<dim3(32,4), dim3(256), 0, stream>>>(act1, wf2, f2b, act2);
  fcm_kernel<2,16,1024,1000,1><<<dim3(32,8), dim3(256), 0, stream>>>(act2, wf3, f3b, (float*)d_out);
}